// Round 16
// baseline (269.254 us; speedup 1.0000x reference)
//
#include <hip/hip_runtime.h>
#include <hip/hip_bf16.h>
#include <stdint.h>

// ---------------- types / helpers ----------------
typedef __attribute__((ext_vector_type(8))) short bf16x8;
typedef __attribute__((ext_vector_type(4))) short bf16x4;
typedef __attribute__((ext_vector_type(4))) float f32x4;
typedef __attribute__((ext_vector_type(4))) int   i32x4;
typedef __attribute__((ext_vector_type(2))) int   i32x2;

#define DEV static __device__ __forceinline__

DEV float bf2f(short s) {
    unsigned u = ((unsigned)(unsigned short)s) << 16;
    return __builtin_bit_cast(float, u);
}
DEV short f2bf(float f) {  // RNE (software; prep paths)
    unsigned u = __builtin_bit_cast(unsigned, f);
    unsigned r = u + 0x7fffu + ((u >> 16) & 1u);
    return (short)(r >> 16);
}
DEV unsigned cvt_pk_bf16(float lo, float hi) {  // single HW instr
    unsigned r;
    asm("v_cvt_pk_bf16_f32 %0, %1, %2" : "=v"(r) : "v"(lo), "v"(hi));
    return r;
}
DEV void async_copy16(void* lds, const void* g) {  // DMA: lds[base + lane*16] <- g(lane)
    __builtin_amdgcn_global_load_lds((const __attribute__((address_space(1))) void*)g,
                                     (__attribute__((address_space(3))) void*)lds, 16, 0, 0);
}

// problem constants
#define PTOT 32768
#define NEXP2 (-2.885390081777927f)   // -2*log2(e)

// ws byte offsets
#define WS_WC1F 0          // wc1f: 16384 shorts
#define WS_WC2F 32768      // wc2f: 16384 shorts
#define WS_WD1F 65536      // wd1f: 147456 shorts
#define WS_WF   360448     // Wf:   589824 shorts
#define WS_EKT  1540096
#define WS_EN   2719744    // enF: 16.8 MB
#define WS_XT   19496960   // xT8: 8*66*32*66*8 bf16 = 17842176 B ; total ~37.3 MB

// ---------------- prep: fragment-major weight reorder + bf16 cast ----------------
__global__ __launch_bounds__(256) void k_prep(const float* __restrict__ W, const float* __restrict__ w_d1,
                                              const float* __restrict__ w_c1, const float* __restrict__ w_c2,
                                              short* __restrict__ Wf, short* __restrict__ wd1f,
                                              short* __restrict__ wc1f, short* __restrict__ wc2f) {
    int t = blockIdx.x * 256 + threadIdx.x;
    if (t < 589824) {
        int i = t & 7, lane = (t >> 3) & 63, ot = (t >> 9) & 15, kt = t >> 13;   // kt < 72
        int o = ot * 16 + (lane & 15);
        int n = (kt & 7) * 32 + (lane >> 4) * 8 + i;
        Wf[t] = f2bf(2.0f * W[o * 2304 + n * 9 + (kt >> 3)]);
    } else if (t < 589824 + 147456) {
        int t2 = t - 589824;
        int i = t2 & 7, lane = (t2 >> 3) & 63, wv = (t2 >> 9) & 3, kc = t2 >> 11; // kc < 72
        int m = wv * 16 + (lane & 15);
        int n = (kc & 7) * 32 + (lane >> 4) * 8 + i;
        wd1f[t2] = f2bf(w_d1[m * 2304 + n * 9 + (kc >> 3)]);
    } else if (t < 589824 + 147456 + 16384) {
        int t3 = t - (589824 + 147456);
        int i = t3 & 7, lane = (t3 >> 3) & 63, wv = (t3 >> 9) & 3, s = t3 >> 11;  // s < 8
        int m = wv * 16 + (lane & 15);
        int n = s * 32 + (lane >> 4) * 8 + i;
        wc1f[t3] = f2bf(w_c1[m * 256 + n]);
    } else if (t < 589824 + 147456 + 32768) {
        int t4 = t - (589824 + 147456 + 16384);
        int i = t4 & 7, lane = (t4 >> 3) & 63, ot = (t4 >> 9) & 15, s = t4 >> 13; // s < 2
        int o = ot * 16 + (lane & 15);
        int kk = s * 32 + (lane >> 4) * 8 + i;
        wc2f[t4] = f2bf(w_c2[o * 64 + kk]);
    }
}

// ---------------- prep: padded x in n-pack layout ----------------
// xT8[b][hp][np][wp][8] bf16 : hp,wp in [0,66) (borders zero), np = n>>3 (32 packs).
__global__ __launch_bounds__(256) void k_prep_xt(const float* __restrict__ x, short* __restrict__ xT8) {
    __shared__ short t[64 * 74];
    const int rw = ((blockIdx.x & 7) << 6) + (blockIdx.x >> 3);   // 512: b = rw>>6, hr = rw&63
    const int b = rw >> 6, hr = rw & 63;
    const int tid = threadIdx.x;
    const int hp = hr + 1;
    #define XI(HP, NP, WP) ((((size_t)(b) * 66 + (HP)) * 32 + (NP)) * 66 + (WP)) * 8
    if (tid < 64) {   // zero wp borders for this row
        int np = tid & 31, wp = (tid & 32) ? 65 : 0;
        *(i32x4*)(xT8 + XI(hp, np, wp)) = i32x4{0, 0, 0, 0};
    }
    if (hr == 0) {    // zero full hp=0,65 planes for this b
        for (int i = tid; i < 2 * 32 * 66; i += 256) {
            int pl = (i >= 32 * 66) ? 65 : 0;
            int rem = (i >= 32 * 66) ? i - 32 * 66 : i;
            int np = rem / 66, wp = rem - np * 66;
            *(i32x4*)(xT8 + XI(pl, np, wp)) = i32x4{0, 0, 0, 0};
        }
    }
    const int dn = tid >> 6, w = tid & 63;
    for (int p = 0; p < 4; ++p) {
        __syncthreads();
        #pragma unroll
        for (int jj = 0; jj < 16; ++jj) {
            int n = p * 64 + dn * 16 + jj;
            t[w * 74 + dn * 16 + jj] = f2bf(x[(((size_t)(b * 256 + n) * 64) + hr) * 64 + w]);
        }
        __syncthreads();
        #pragma unroll
        for (int q = 0; q < 2; ++q) {
            int nl = q * 4 + dn;
            *(bf16x8*)(xT8 + XI(hp, p * 8 + nl, w + 1)) = *(const bf16x8*)(t + w * 74 + nl * 8);
        }
    }
    #undef XI
}

// ---------------- branch kernel: enF (= e^{-2c}) and ekT (= e^{-2d}) ----------------
// enF layout per 64px row-block: [8 n0c][4 n8][64 px][8] (16B lane-contiguous for k_final).
#define BR_YD_OFF  9216
#define BR_ENT_OFF (BR_YD_OFF + 17152)
#define BR_TOTAL   (BR_ENT_OFF + 33792)   // 60160

__global__ __launch_bounds__(512, 4) void k_branch(const short* __restrict__ xT8,
        const float* __restrict__ b_c1, const float* __restrict__ b_c2,
        const float* __restrict__ b_d1, const float* __restrict__ w_d2, const float* __restrict__ b_d2,
        const short* __restrict__ wc1f, const short* __restrict__ wc2f, const short* __restrict__ wd1f,
        short* __restrict__ enF, float* __restrict__ ekT) {
    extern __shared__ char smem[];
    short* yc  = (short*)smem;
    float* ydl = (float*)(smem + BR_YD_OFF);
    short* ent = (short*)(smem + BR_ENT_OFF);

    const int rw = ((blockIdx.x & 7) << 6) + (blockIdx.x >> 3);  // XCD x <- batch x
    const int b = rw >> 6, h = rw & 63;
    const int p0 = rw << 6;
    const int tid = threadIdx.x;
    const int lane = tid & 63, wave = tid >> 6;
    const int l16 = lane & 15, lg = lane >> 4;
    const int wn = wave & 3, wm = wave >> 2;   // 2 (M) x 4 (N)
    const int cm = wn * 16 + l16;
    const size_t b66h = (size_t)(b * 66 + h);
    const int wcol = wm * 32 + l16;

    #define CONV_A(DST, KC) {                                                           \
        int k9_ = (KC) >> 3;                                                            \
        int kh_ = (k9_ * 11) >> 5, kw_ = k9_ - 3 * kh_;                                 \
        const short* xa_ = xT8 + (((b66h + kh_) * 32 + ((KC) & 7) * 4 + lg) * 66        \
                                  + wcol + kw_) * 8;                                    \
        DST[0] = *(const bf16x8*)(xa_);                                                 \
        DST[1] = *(const bf16x8*)(xa_ + 128);                                           \
    }

    // ---- GEMM1: yc = relu(x . w_c1^T + b_c1)
    {
        f32x4 acc[2] = {};
        const short* wp_ = wc1f + wn * 512 + lane * 8;
        const short* xg1 = xT8 + (((b66h + 1) * 32 + lg) * 66 + wcol + 1) * 8;  // + s*2112
        bf16x8 bcur = *(const bf16x8*)(wp_);
        bf16x8 a0 = *(const bf16x8*)(xg1), a1 = *(const bf16x8*)(xg1 + 128);
        #pragma unroll
        for (int s = 0; s < 8; ++s) {
            bf16x8 bc = bcur, c0 = a0, c1 = a1;
            if (s < 7) {
                bcur = *(const bf16x8*)(wp_ + (s + 1) * 2048);
                a0 = *(const bf16x8*)(xg1 + (s + 1) * 2112);
                a1 = *(const bf16x8*)(xg1 + (s + 1) * 2112 + 128);
            }
            acc[0] = __builtin_amdgcn_mfma_f32_16x16x32_bf16(c0, bc, acc[0], 0, 0, 0);
            acc[1] = __builtin_amdgcn_mfma_f32_16x16x32_bf16(c1, bc, acc[1], 0, 0, 0);
        }
        float bias = b_c1[cm];
        #pragma unroll
        for (int mt = 0; mt < 2; ++mt)
            #pragma unroll
            for (int r = 0; r < 4; ++r) {
                int px = wm * 32 + mt * 16 + lg * 4 + r;
                float v = acc[mt][r] + bias;
                yc[px * 72 + cm] = f2bf(v > 0.f ? v : 0.f);
            }
    }

    // ---- conv GEMM: yd = relu(conv3x3 + b_d1)
    {
        f32x4 acc[2] = {};
        const short* wp_ = wd1f + wn * 512 + lane * 8;   // kc stride 2048
        bf16x8 b0 = *(const bf16x8*)(wp_);
        bf16x8 b1 = *(const bf16x8*)(wp_ + 2048);
        bf16x8 b2 = *(const bf16x8*)(wp_ + 4096);
        bf16x8 aA[2], aB[2], aC[2];
        CONV_A(aA, 0) CONV_A(aB, 1) CONV_A(aC, 2)
        for (int kc = 0; kc < 72; kc += 3) {
            {
                bf16x8 c0 = aA[0], c1 = aA[1], bc = b0;
                int cn = (kc + 3 < 72) ? kc + 3 : 71;
                CONV_A(aA, cn)
                b0 = *(const bf16x8*)(wp_ + cn * 2048);
                acc[0] = __builtin_amdgcn_mfma_f32_16x16x32_bf16(c0, bc, acc[0], 0, 0, 0);
                acc[1] = __builtin_amdgcn_mfma_f32_16x16x32_bf16(c1, bc, acc[1], 0, 0, 0);
            }
            {
                bf16x8 c0 = aB[0], c1 = aB[1], bc = b1;
                int cn = (kc + 4 < 72) ? kc + 4 : 71;
                CONV_A(aB, cn)
                b1 = *(const bf16x8*)(wp_ + cn * 2048);
                acc[0] = __builtin_amdgcn_mfma_f32_16x16x32_bf16(c0, bc, acc[0], 0, 0, 0);
                acc[1] = __builtin_amdgcn_mfma_f32_16x16x32_bf16(c1, bc, acc[1], 0, 0, 0);
            }
            {
                bf16x8 c0 = aC[0], c1 = aC[1], bc = b2;
                int cn = (kc + 5 < 72) ? kc + 5 : 71;
                CONV_A(aC, cn)
                b2 = *(const bf16x8*)(wp_ + cn * 2048);
                acc[0] = __builtin_amdgcn_mfma_f32_16x16x32_bf16(c0, bc, acc[0], 0, 0, 0);
                acc[1] = __builtin_amdgcn_mfma_f32_16x16x32_bf16(c1, bc, acc[1], 0, 0, 0);
            }
        }
        float bias = b_d1[cm];
        #pragma unroll
        for (int mt = 0; mt < 2; ++mt)
            #pragma unroll
            for (int r = 0; r < 4; ++r) {
                int px = wm * 32 + mt * 16 + lg * 4 + r;
                float v = acc[mt][r] + bias;
                ydl[px * 67 + cm] = v > 0.f ? v : 0.f;
            }
    }
    #undef CONV_A
    __syncthreads();   // yc + ydl ready

    // ---- GEMM2 ; ent = exp(-2c)
    {
        f32x4 acc[2][4] = {};
        #pragma unroll
        for (int s = 0; s < 2; ++s) {
            int k0 = s * 32;
            bf16x8 afr[2], bfr[4];
            #pragma unroll
            for (int mt = 0; mt < 2; ++mt)
                afr[mt] = *(const bf16x8*)(yc + (wm * 32 + mt * 16 + l16) * 72 + k0 + lg * 8);
            #pragma unroll
            for (int nt = 0; nt < 4; ++nt)
                bfr[nt] = *(const bf16x8*)(wc2f + s * 8192 + (wn * 4 + nt) * 512 + lane * 8);
            #pragma unroll
            for (int mt = 0; mt < 2; ++mt)
                #pragma unroll
                for (int nt = 0; nt < 4; ++nt)
                    acc[mt][nt] = __builtin_amdgcn_mfma_f32_16x16x32_bf16(afr[mt], bfr[nt], acc[mt][nt], 0, 0, 0);
        }
        #pragma unroll
        for (int nt = 0; nt < 4; ++nt) {
            int nc = wn * 64 + nt * 16 + l16;
            float bias = b_c2[nc];
            #pragma unroll
            for (int mt = 0; mt < 2; ++mt)
                #pragma unroll
                for (int r = 0; r < 4; ++r) {
                    int px = wm * 32 + mt * 16 + lg * 4 + r;
                    float cv = acc[mt][nt][r] + bias;
                    ent[px * 264 + nc] = f2bf(exp2f(NEXP2 * cv));
                }
        }
    }

    // ---- d / ekT
    for (int t = tid; t < 576; t += 512) {
        int k = t >> 6, px = t & 63;
        float sum = b_d2[k];
        const float* yr = ydl + px * 67;
        const float* wr = w_d2 + k * 64;
        #pragma unroll 8
        for (int m = 0; m < 64; ++m) sum += yr[m] * wr[m];
        ekT[(size_t)k * PTOT + p0 + px] = exp2f(NEXP2 * sum);
    }
    __syncthreads();   // ent ready

    // ---- enF store: [8 n0c][4 n8][64 px][8], lane-contiguous 16B
    for (int i = tid; i < 2048; i += 512) {
        int px = i & 63, seg = i >> 6;   // seg = n>>3, 0..31
        *(bf16x8*)(enF + (size_t)p0 * 256 + (seg >> 2) * 2048 + (seg & 3) * 512 + px * 8)
            = *(const bf16x8*)(ent + px * 264 + seg * 8);
    }
}

// ---------------- final kernel: merged-o m97-style K-loop, 8 waves ----------------
// 512 blocks (one per row, XCD-swizzled) x (64px x 256o), 512 thr (8 waves).
// Wave w owns o-slice [w*32, w*32+32): acc[4][2], 8 MFMA/step.
// zbuild: thread (lane=px, wave=slot) computes 4 bf16 of z[px][c8*32 + wave*4 ..+4];
// en for all 8 c8 chunks held in registers (bf16x4 x 8). zF fragment-major (0 conflicts).
// 2 blocks/CU x 8 waves = 16 waves/CU (4/SIMD). One barrier per K-step.
#define FN4_Z1    4096
#define FN4_B0    8192
#define FN4_B1    24576
#define FN4_EKL   40960
#define FN4_TOTAL 43264

__global__ __launch_bounds__(512, 4) void k_final(const short* __restrict__ xT8,
        const short* __restrict__ Wf, const short* __restrict__ enF, const float* __restrict__ ekT,
        float* __restrict__ out) {
    extern __shared__ char smem[];
    short* z0  = (short*)smem;                 // [4 mt][64 lane][8]
    short* z1  = (short*)(smem + FN4_Z1);
    short* Bl0 = (short*)(smem + FN4_B0);      // [16 ot][512]
    short* Bl1 = (short*)(smem + FN4_B1);
    float* ekl = (float*)(smem + FN4_EKL);     // [9][64]

    const int rw = ((blockIdx.x & 7) << 6) + (blockIdx.x >> 3);  // 512, XCD-chunked
    const int b = rw >> 6, h = rw & 63;
    const int p0 = rw << 6;
    const int tid = threadIdx.x;
    const int lane = tid & 63, wave = tid >> 6;   // 8 waves
    const int l16 = lane & 15, lg = lane >> 4;

    for (int i = tid; i < 576; i += 512)
        ekl[i] = ekT[(size_t)(i >> 6) * PTOT + p0 + (i & 63)];

    const size_t b66h = (size_t)(b * 66 + h);
    // zbuild thread: px = lane, n = c8*32 + wave*4 + j (j=0..3)
    const int zpx = lane;
    const int wh = wave >> 1, wl = wave & 1;
    // x: np = c8*4 + wh, in-pack offset wl*4 ; + kh*16896 + c8*2112 + kw*8
    const short* xb0 = xT8 + (b66h * 32 + wh) * 528 + zpx * 8 + wl * 4;
    // en regs: one bf16x4 per c8
    bf16x4 e_regs[8];
    {
        const short* enb = enF + (size_t)p0 * 256 + wh * 512 + zpx * 8 + wl * 4;
        #pragma unroll
        for (int c8 = 0; c8 < 8; ++c8) e_regs[c8] = *(const bf16x4*)(enb + c8 * 2048);
    }
    // z write slot: 8B at mt*512 + ((zpx&15) + wh*16)*8 + wl*4  (shorts)
    const int zwoff = (zpx >> 4) * 512 + ((zpx & 15) + wh * 16) * 8 + wl * 4;
    const char* WfB = (const char*)Wf;

    #define DMA_B(KC, BUF) {                                                            \
        _Pragma("unroll")                                                               \
        for (int c = 0; c < 2; ++c) {                                                   \
            const char* g_ = WfB + (size_t)(KC) * 16384 + (wave * 2 + c) * 1024 + lane * 16; \
            async_copy16((char*)(BUF) + (wave * 2 + c) * 1024, g_);                     \
        }                                                                               \
    }
    bf16x4 xr;
    #define XLOAD(KC2) {                                                                \
        int k3_ = (KC2) >> 3, c8_ = (KC2) & 7;                                          \
        int kh_ = (k3_ * 11) >> 5, kw_ = k3_ - 3 * kh_;                                 \
        xr = *(const bf16x4*)(xb0 + kh_ * 16896 + c8_ * 2112 + kw_ * 8);                \
    }
    #define ZBUILD(ZBUF, KC1) {                                                         \
        bf16x4 er = e_regs[(KC1) & 7];                                                  \
        float ekv = ekl[((KC1) >> 3) * 64 + zpx];                                       \
        float q0 = __builtin_fmaf(ekv, bf2f(er[0]), 1.0f);                              \
        float q1 = __builtin_fmaf(ekv, bf2f(er[1]), 1.0f);                              \
        float q2 = __builtin_fmaf(ekv, bf2f(er[2]), 1.0f);                              \
        float q3 = __builtin_fmaf(ekv, bf2f(er[3]), 1.0f);                              \
        i32x2 zz;                                                                       \
        zz[0] = cvt_pk_bf16(bf2f(xr[0]) * __builtin_amdgcn_rcpf(q0),                    \
                            bf2f(xr[1]) * __builtin_amdgcn_rcpf(q1));                   \
        zz[1] = cvt_pk_bf16(bf2f(xr[2]) * __builtin_amdgcn_rcpf(q2),                    \
                            bf2f(xr[3]) * __builtin_amdgcn_rcpf(q3));                   \
        *(i32x2*)((ZBUF) + zwoff) = zz;                                                 \
    }

    // prologue
    DMA_B(0, Bl0)
    XLOAD(0)
    __syncthreads();          // ekl staged + B(0) drained
    ZBUILD(z0, 0)
    XLOAD(1)
    __syncthreads();          // z(0) visible

    f32x4 acc[4][2] = {};

    #pragma unroll 2
    for (int kc = 0; kc < 72; ++kc) {
        short* zcur = (kc & 1) ? z1 : z0;
        short* znxt = (kc & 1) ? z0 : z1;
        short* bcur = (kc & 1) ? Bl1 : Bl0;
        short* bnxt = (kc & 1) ? Bl0 : Bl1;
        if (kc < 71) {
            DMA_B(kc + 1, bnxt)       // in flight across this step; drained at barrier
            ZBUILD(znxt, kc + 1)
        }
        if (kc < 70) XLOAD(kc + 2)
        bf16x8 afr[4], bfr[2];
        #pragma unroll
        for (int mt = 0; mt < 4; ++mt)
            afr[mt] = *(const bf16x8*)(zcur + mt * 512 + lane * 8);
        bfr[0] = *(const bf16x8*)(bcur + (wave * 2 + 0) * 512 + lane * 8);
        bfr[1] = *(const bf16x8*)(bcur + (wave * 2 + 1) * 512 + lane * 8);
        __builtin_amdgcn_s_setprio(1);
        #pragma unroll
        for (int mt = 0; mt < 4; ++mt) {
            acc[mt][0] = __builtin_amdgcn_mfma_f32_16x16x32_bf16(afr[mt], bfr[0], acc[mt][0], 0, 0, 0);
            acc[mt][1] = __builtin_amdgcn_mfma_f32_16x16x32_bf16(afr[mt], bfr[1], acc[mt][1], 0, 0, 0);
        }
        __builtin_amdgcn_s_setprio(0);
        __syncthreads();
    }
    #undef ZBUILD
    #undef XLOAD
    #undef DMA_B

    // epilogue: o = wave*32 + nt*16 + l16 ; px = mt*16 + lg*4 + r
    #pragma unroll
    for (int mt = 0; mt < 4; ++mt)
        #pragma unroll
        for (int nt = 0; nt < 2; ++nt) {
            int o = wave * 32 + nt * 16 + l16;
            float* d = out + (((size_t)b * 256 + o) * 64 + h) * 64 + mt * 16 + lg * 4;
            *(f32x4*)d = acc[mt][nt];
        }
}

// ---------------- launcher ----------------
extern "C" void kernel_launch(void* const* d_in, const int* in_sizes, int n_in,
                              void* d_out, int out_size, void* d_ws, size_t ws_size,
                              hipStream_t stream) {
    const float* x    = (const float*)d_in[0];
    const float* w_c1 = (const float*)d_in[1];
    const float* b_c1 = (const float*)d_in[2];
    const float* w_c2 = (const float*)d_in[3];
    const float* b_c2 = (const float*)d_in[4];
    const float* w_d1 = (const float*)d_in[5];
    const float* b_d1 = (const float*)d_in[6];
    const float* w_d2 = (const float*)d_in[7];
    const float* b_d2 = (const float*)d_in[8];
    const float* Wt   = (const float*)d_in[9];
    float* out = (float*)d_out;
    char* ws = (char*)d_ws;

    short* wc1f = (short*)(ws + WS_WC1F);
    short* wc2f = (short*)(ws + WS_WC2F);
    short* wd1f = (short*)(ws + WS_WD1F);
    short* Wf   = (short*)(ws + WS_WF);
    float* ekT  = (float*)(ws + WS_EKT);
    short* enF  = (short*)(ws + WS_EN);
    short* xT8  = (short*)(ws + WS_XT);

    (void)hipFuncSetAttribute((const void*)k_branch, hipFuncAttributeMaxDynamicSharedMemorySize, BR_TOTAL);
    (void)hipFuncSetAttribute((const void*)k_final,  hipFuncAttributeMaxDynamicSharedMemorySize, FN4_TOTAL);

    k_prep<<<3008, 256, 0, stream>>>(Wt, w_d1, w_c1, w_c2, Wf, wd1f, wc1f, wc2f);
    k_prep_xt<<<512, 256, 0, stream>>>(x, xT8);
    k_branch<<<512, 512, BR_TOTAL, stream>>>(xT8, b_c1, b_c2, b_d1, w_d2, b_d2, wc1f, wc2f, wd1f, enF, ekT);
    k_final<<<512, 512, FN4_TOTAL, stream>>>(xT8, Wf, enF, ekT, out);
}

// Round 18
// 112.251 us; speedup vs baseline: 2.3987x; 2.3987x over previous
//
#include <hip/hip_runtime.h>
#include <hip/hip_bf16.h>
#include <stdint.h>

// ---------------- types / helpers ----------------
typedef __attribute__((ext_vector_type(8))) short bf16x8;
typedef __attribute__((ext_vector_type(4))) short bf16x4;
typedef __attribute__((ext_vector_type(4))) float f32x4;
typedef __attribute__((ext_vector_type(4))) int   i32x4;
typedef __attribute__((ext_vector_type(2))) int   i32x2;

#define DEV static __device__ __forceinline__

DEV float bf2f(short s) {
    unsigned u = ((unsigned)(unsigned short)s) << 16;
    return __builtin_bit_cast(float, u);
}
DEV short f2bf(float f) {  // RNE (software; prep paths)
    unsigned u = __builtin_bit_cast(unsigned, f);
    unsigned r = u + 0x7fffu + ((u >> 16) & 1u);
    return (short)(r >> 16);
}
DEV unsigned cvt_pk_bf16(float lo, float hi) {  // single HW instr
    unsigned r;
    asm("v_cvt_pk_bf16_f32 %0, %1, %2" : "=v"(r) : "v"(lo), "v"(hi));
    return r;
}
DEV void async_copy16(void* lds, const void* g) {  // DMA: lds[base + lane*16] <- g(lane)
    __builtin_amdgcn_global_load_lds((const __attribute__((address_space(1))) void*)g,
                                     (__attribute__((address_space(3))) void*)lds, 16, 0, 0);
}

// problem constants
#define PTOT 32768
#define NEXP2 (-2.885390081777927f)   // -2*log2(e)

// ws byte offsets
#define WS_WC1F 0          // wc1f: 16384 shorts
#define WS_WC2F 32768      // wc2f: 16384 shorts
#define WS_WD1F 65536      // wd1f: 147456 shorts
#define WS_WF   360448     // Wf:   589824 shorts
#define WS_EKT  1540096
#define WS_EN   2719744    // enF: 16.8 MB
#define WS_XT   19496960   // xT8: 8*66*32*66*8 bf16 = 17842176 B ; total ~37.3 MB

// ---------------- prep: fragment-major weight reorder + bf16 cast ----------------
__global__ __launch_bounds__(256) void k_prep(const float* __restrict__ W, const float* __restrict__ w_d1,
                                              const float* __restrict__ w_c1, const float* __restrict__ w_c2,
                                              short* __restrict__ Wf, short* __restrict__ wd1f,
                                              short* __restrict__ wc1f, short* __restrict__ wc2f) {
    int t = blockIdx.x * 256 + threadIdx.x;
    if (t < 589824) {
        int i = t & 7, lane = (t >> 3) & 63, ot = (t >> 9) & 15, kt = t >> 13;   // kt < 72
        int o = ot * 16 + (lane & 15);
        int n = (kt & 7) * 32 + (lane >> 4) * 8 + i;
        Wf[t] = f2bf(2.0f * W[o * 2304 + n * 9 + (kt >> 3)]);
    } else if (t < 589824 + 147456) {
        int t2 = t - 589824;
        int i = t2 & 7, lane = (t2 >> 3) & 63, wv = (t2 >> 9) & 3, kc = t2 >> 11; // kc < 72
        int m = wv * 16 + (lane & 15);
        int n = (kc & 7) * 32 + (lane >> 4) * 8 + i;
        wd1f[t2] = f2bf(w_d1[m * 2304 + n * 9 + (kc >> 3)]);
    } else if (t < 589824 + 147456 + 16384) {
        int t3 = t - (589824 + 147456);
        int i = t3 & 7, lane = (t3 >> 3) & 63, wv = (t3 >> 9) & 3, s = t3 >> 11;  // s < 8
        int m = wv * 16 + (lane & 15);
        int n = s * 32 + (lane >> 4) * 8 + i;
        wc1f[t3] = f2bf(w_c1[m * 256 + n]);
    } else if (t < 589824 + 147456 + 32768) {
        int t4 = t - (589824 + 147456 + 16384);
        int i = t4 & 7, lane = (t4 >> 3) & 63, ot = (t4 >> 9) & 15, s = t4 >> 13; // s < 2
        int o = ot * 16 + (lane & 15);
        int kk = s * 32 + (lane >> 4) * 8 + i;
        wc2f[t4] = f2bf(w_c2[o * 64 + kk]);
    }
}

// ---------------- prep: padded x in n-pack layout ----------------
// xT8[b][hp][np][wp][8] bf16 : hp,wp in [0,66) (borders zero), np = n>>3 (32 packs).
__global__ __launch_bounds__(256) void k_prep_xt(const float* __restrict__ x, short* __restrict__ xT8) {
    __shared__ short t[64 * 74];
    const int rw = ((blockIdx.x & 7) << 6) + (blockIdx.x >> 3);   // 512: b = rw>>6, hr = rw&63
    const int b = rw >> 6, hr = rw & 63;
    const int tid = threadIdx.x;
    const int hp = hr + 1;
    #define XI(HP, NP, WP) ((((size_t)(b) * 66 + (HP)) * 32 + (NP)) * 66 + (WP)) * 8
    if (tid < 64) {   // zero wp borders for this row
        int np = tid & 31, wp = (tid & 32) ? 65 : 0;
        *(i32x4*)(xT8 + XI(hp, np, wp)) = i32x4{0, 0, 0, 0};
    }
    if (hr == 0) {    // zero full hp=0,65 planes for this b
        for (int i = tid; i < 2 * 32 * 66; i += 256) {
            int pl = (i >= 32 * 66) ? 65 : 0;
            int rem = (i >= 32 * 66) ? i - 32 * 66 : i;
            int np = rem / 66, wp = rem - np * 66;
            *(i32x4*)(xT8 + XI(pl, np, wp)) = i32x4{0, 0, 0, 0};
        }
    }
    const int dn = tid >> 6, w = tid & 63;
    for (int p = 0; p < 4; ++p) {
        __syncthreads();
        #pragma unroll
        for (int jj = 0; jj < 16; ++jj) {
            int n = p * 64 + dn * 16 + jj;
            t[w * 74 + dn * 16 + jj] = f2bf(x[(((size_t)(b * 256 + n) * 64) + hr) * 64 + w]);
        }
        __syncthreads();
        #pragma unroll
        for (int q = 0; q < 2; ++q) {
            int nl = q * 4 + dn;
            *(bf16x8*)(xT8 + XI(hp, p * 8 + nl, w + 1)) = *(const bf16x8*)(t + w * 74 + nl * 8);
        }
    }
    #undef XI
}

// ---------------- branch kernel: enF (= e^{-2c}) and ekT (= e^{-2d}) ----------------
// enF layout per 64px row-block: [8 n0c][4 n8][64 px][8] (16B lane-contiguous for k_final).
#define BR_YD_OFF  9216
#define BR_ENT_OFF (BR_YD_OFF + 17152)
#define BR_TOTAL   (BR_ENT_OFF + 33792)   // 60160

__global__ __launch_bounds__(512, 4) void k_branch(const short* __restrict__ xT8,
        const float* __restrict__ b_c1, const float* __restrict__ b_c2,
        const float* __restrict__ b_d1, const float* __restrict__ w_d2, const float* __restrict__ b_d2,
        const short* __restrict__ wc1f, const short* __restrict__ wc2f, const short* __restrict__ wd1f,
        short* __restrict__ enF, float* __restrict__ ekT) {
    extern __shared__ char smem[];
    short* yc  = (short*)smem;
    float* ydl = (float*)(smem + BR_YD_OFF);
    short* ent = (short*)(smem + BR_ENT_OFF);

    const int rw = ((blockIdx.x & 7) << 6) + (blockIdx.x >> 3);  // XCD x <- batch x
    const int b = rw >> 6, h = rw & 63;
    const int p0 = rw << 6;
    const int tid = threadIdx.x;
    const int lane = tid & 63, wave = tid >> 6;
    const int l16 = lane & 15, lg = lane >> 4;
    const int wn = wave & 3, wm = wave >> 2;   // 2 (M) x 4 (N)
    const int cm = wn * 16 + l16;
    const size_t b66h = (size_t)(b * 66 + h);
    const int wcol = wm * 32 + l16;

    #define CONV_A(DST, KC) {                                                           \
        int k9_ = (KC) >> 3;                                                            \
        int kh_ = (k9_ * 11) >> 5, kw_ = k9_ - 3 * kh_;                                 \
        const short* xa_ = xT8 + (((b66h + kh_) * 32 + ((KC) & 7) * 4 + lg) * 66        \
                                  + wcol + kw_) * 8;                                    \
        DST[0] = *(const bf16x8*)(xa_);                                                 \
        DST[1] = *(const bf16x8*)(xa_ + 128);                                           \
    }

    // ---- GEMM1: yc = relu(x . w_c1^T + b_c1)
    {
        f32x4 acc[2] = {};
        const short* wp_ = wc1f + wn * 512 + lane * 8;
        const short* xg1 = xT8 + (((b66h + 1) * 32 + lg) * 66 + wcol + 1) * 8;  // + s*2112
        bf16x8 bcur = *(const bf16x8*)(wp_);
        bf16x8 a0 = *(const bf16x8*)(xg1), a1 = *(const bf16x8*)(xg1 + 128);
        #pragma unroll
        for (int s = 0; s < 8; ++s) {
            bf16x8 bc = bcur, c0 = a0, c1 = a1;
            if (s < 7) {
                bcur = *(const bf16x8*)(wp_ + (s + 1) * 2048);
                a0 = *(const bf16x8*)(xg1 + (s + 1) * 2112);
                a1 = *(const bf16x8*)(xg1 + (s + 1) * 2112 + 128);
            }
            acc[0] = __builtin_amdgcn_mfma_f32_16x16x32_bf16(c0, bc, acc[0], 0, 0, 0);
            acc[1] = __builtin_amdgcn_mfma_f32_16x16x32_bf16(c1, bc, acc[1], 0, 0, 0);
        }
        float bias = b_c1[cm];
        #pragma unroll
        for (int mt = 0; mt < 2; ++mt)
            #pragma unroll
            for (int r = 0; r < 4; ++r) {
                int px = wm * 32 + mt * 16 + lg * 4 + r;
                float v = acc[mt][r] + bias;
                yc[px * 72 + cm] = f2bf(v > 0.f ? v : 0.f);
            }
    }

    // ---- conv GEMM: yd = relu(conv3x3 + b_d1)
    {
        f32x4 acc[2] = {};
        const short* wp_ = wd1f + wn * 512 + lane * 8;   // kc stride 2048
        bf16x8 b0 = *(const bf16x8*)(wp_);
        bf16x8 b1 = *(const bf16x8*)(wp_ + 2048);
        bf16x8 b2 = *(const bf16x8*)(wp_ + 4096);
        bf16x8 aA[2], aB[2], aC[2];
        CONV_A(aA, 0) CONV_A(aB, 1) CONV_A(aC, 2)
        for (int kc = 0; kc < 72; kc += 3) {
            {
                bf16x8 c0 = aA[0], c1 = aA[1], bc = b0;
                int cn = (kc + 3 < 72) ? kc + 3 : 71;
                CONV_A(aA, cn)
                b0 = *(const bf16x8*)(wp_ + cn * 2048);
                acc[0] = __builtin_amdgcn_mfma_f32_16x16x32_bf16(c0, bc, acc[0], 0, 0, 0);
                acc[1] = __builtin_amdgcn_mfma_f32_16x16x32_bf16(c1, bc, acc[1], 0, 0, 0);
            }
            {
                bf16x8 c0 = aB[0], c1 = aB[1], bc = b1;
                int cn = (kc + 4 < 72) ? kc + 4 : 71;
                CONV_A(aB, cn)
                b1 = *(const bf16x8*)(wp_ + cn * 2048);
                acc[0] = __builtin_amdgcn_mfma_f32_16x16x32_bf16(c0, bc, acc[0], 0, 0, 0);
                acc[1] = __builtin_amdgcn_mfma_f32_16x16x32_bf16(c1, bc, acc[1], 0, 0, 0);
            }
            {
                bf16x8 c0 = aC[0], c1 = aC[1], bc = b2;
                int cn = (kc + 5 < 72) ? kc + 5 : 71;
                CONV_A(aC, cn)
                b2 = *(const bf16x8*)(wp_ + cn * 2048);
                acc[0] = __builtin_amdgcn_mfma_f32_16x16x32_bf16(c0, bc, acc[0], 0, 0, 0);
                acc[1] = __builtin_amdgcn_mfma_f32_16x16x32_bf16(c1, bc, acc[1], 0, 0, 0);
            }
        }
        float bias = b_d1[cm];
        #pragma unroll
        for (int mt = 0; mt < 2; ++mt)
            #pragma unroll
            for (int r = 0; r < 4; ++r) {
                int px = wm * 32 + mt * 16 + lg * 4 + r;
                float v = acc[mt][r] + bias;
                ydl[px * 67 + cm] = v > 0.f ? v : 0.f;
            }
    }
    #undef CONV_A
    __syncthreads();   // yc + ydl ready

    // ---- GEMM2 ; ent = exp(-2c)
    {
        f32x4 acc[2][4] = {};
        #pragma unroll
        for (int s = 0; s < 2; ++s) {
            int k0 = s * 32;
            bf16x8 afr[2], bfr[4];
            #pragma unroll
            for (int mt = 0; mt < 2; ++mt)
                afr[mt] = *(const bf16x8*)(yc + (wm * 32 + mt * 16 + l16) * 72 + k0 + lg * 8);
            #pragma unroll
            for (int nt = 0; nt < 4; ++nt)
                bfr[nt] = *(const bf16x8*)(wc2f + s * 8192 + (wn * 4 + nt) * 512 + lane * 8);
            #pragma unroll
            for (int mt = 0; mt < 2; ++mt)
                #pragma unroll
                for (int nt = 0; nt < 4; ++nt)
                    acc[mt][nt] = __builtin_amdgcn_mfma_f32_16x16x32_bf16(afr[mt], bfr[nt], acc[mt][nt], 0, 0, 0);
        }
        #pragma unroll
        for (int nt = 0; nt < 4; ++nt) {
            int nc = wn * 64 + nt * 16 + l16;
            float bias = b_c2[nc];
            #pragma unroll
            for (int mt = 0; mt < 2; ++mt)
                #pragma unroll
                for (int r = 0; r < 4; ++r) {
                    int px = wm * 32 + mt * 16 + lg * 4 + r;
                    float cv = acc[mt][nt][r] + bias;
                    ent[px * 264 + nc] = f2bf(exp2f(NEXP2 * cv));
                }
        }
    }

    // ---- d / ekT
    for (int t = tid; t < 576; t += 512) {
        int k = t >> 6, px = t & 63;
        float sum = b_d2[k];
        const float* yr = ydl + px * 67;
        const float* wr = w_d2 + k * 64;
        #pragma unroll 8
        for (int m = 0; m < 64; ++m) sum += yr[m] * wr[m];
        ekT[(size_t)k * PTOT + p0 + px] = exp2f(NEXP2 * sum);
    }
    __syncthreads();   // ent ready

    // ---- enF store: [8 n0c][4 n8][64 px][8], lane-contiguous 16B
    for (int i = tid; i < 2048; i += 512) {
        int px = i & 63, seg = i >> 6;   // seg = n>>3, 0..31
        *(bf16x8*)(enF + (size_t)p0 * 256 + (seg >> 2) * 2048 + (seg & 3) * 512 + px * 8)
            = *(const bf16x8*)(ent + px * 264 + seg * 8);
    }
}

// ---------------- final kernel: merged-o m97-style K-loop, 8 waves ----------------
// 512 blocks x (64px x 256o), 512 thr (8 waves), acc[4][2]/wave.
// K-loop: outer runtime k3 (0..7) x inner UNROLLED c8 (0..7) + peeled k3=8 tail, so
// e_regs indices and buffer parity are COMPILE-TIME (rule #20; r16 regression).
// r17 bugfix: tail STEP(5) must XLOAD(71) (consumed by STEP(6)'s ZBUILD of z(71)).
#define FN4_Z1    4096
#define FN4_B0    8192
#define FN4_B1    24576
#define FN4_EKL   40960
#define FN4_TOTAL 43264

__global__ __launch_bounds__(512, 4) void k_final(const short* __restrict__ xT8,
        const short* __restrict__ Wf, const short* __restrict__ enF, const float* __restrict__ ekT,
        float* __restrict__ out) {
    extern __shared__ char smem[];
    short* z0  = (short*)smem;                 // [4 mt][64 lane][8]
    short* z1  = (short*)(smem + FN4_Z1);
    short* Bl0 = (short*)(smem + FN4_B0);      // [16 ot][512]
    short* Bl1 = (short*)(smem + FN4_B1);
    float* ekl = (float*)(smem + FN4_EKL);     // [9][64]

    const int rw = ((blockIdx.x & 7) << 6) + (blockIdx.x >> 3);  // 512, XCD-chunked
    const int b = rw >> 6, h = rw & 63;
    const int p0 = rw << 6;
    const int tid = threadIdx.x;
    const int lane = tid & 63, wave = tid >> 6;   // 8 waves
    const int l16 = lane & 15, lg = lane >> 4;

    for (int i = tid; i < 576; i += 512)
        ekl[i] = ekT[(size_t)(i >> 6) * PTOT + p0 + (i & 63)];

    const size_t b66h = (size_t)(b * 66 + h);
    // zbuild thread: px = lane, n = c8*32 + wave*4 + j (j=0..3)
    const int zpx = lane;
    const int wh = wave >> 1, wl = wave & 1;
    const short* xb0 = xT8 + (b66h * 32 + wh) * 528 + zpx * 8 + wl * 4;
    bf16x4 e_regs[8];
    {
        const short* enb = enF + (size_t)p0 * 256 + wh * 512 + zpx * 8 + wl * 4;
        #pragma unroll
        for (int c8 = 0; c8 < 8; ++c8) e_regs[c8] = *(const bf16x4*)(enb + c8 * 2048);
    }
    // z write slot: 8B at mt*512 + ((zpx&15) + wh*16)*8 + wl*4  (shorts)
    const int zwoff = (zpx >> 4) * 512 + ((zpx & 15) + wh * 16) * 8 + wl * 4;
    const char* WfB = (const char*)Wf;

    #define DMA_B(KC, BUF) {                                                            \
        _Pragma("unroll")                                                               \
        for (int c = 0; c < 2; ++c) {                                                   \
            const char* g_ = WfB + (size_t)(KC) * 16384 + (wave * 2 + c) * 1024 + lane * 16; \
            async_copy16((char*)(BUF) + (wave * 2 + c) * 1024, g_);                     \
        }                                                                               \
    }
    bf16x4 xr;
    #define XLOAD(KC2) {                                                                \
        int k3_ = (KC2) >> 3, c8_ = (KC2) & 7;                                          \
        int kh_ = (k3_ * 11) >> 5, kw_ = k3_ - 3 * kh_;                                 \
        xr = *(const bf16x4*)(xb0 + kh_ * 16896 + c8_ * 2112 + kw_ * 8);                \
    }
    // EIDX must be a compile-time constant (register-resident e_regs)
    #define ZBUILD(ZBUF, EKROW, EIDX) {                                                 \
        bf16x4 er = e_regs[EIDX];                                                       \
        float ekv = ekl[(EKROW) * 64 + zpx];                                            \
        float q0 = __builtin_fmaf(ekv, bf2f(er[0]), 1.0f);                              \
        float q1 = __builtin_fmaf(ekv, bf2f(er[1]), 1.0f);                              \
        float q2 = __builtin_fmaf(ekv, bf2f(er[2]), 1.0f);                              \
        float q3 = __builtin_fmaf(ekv, bf2f(er[3]), 1.0f);                              \
        i32x2 zz;                                                                       \
        zz[0] = cvt_pk_bf16(bf2f(xr[0]) * __builtin_amdgcn_rcpf(q0),                    \
                            bf2f(xr[1]) * __builtin_amdgcn_rcpf(q1));                   \
        zz[1] = cvt_pk_bf16(bf2f(xr[2]) * __builtin_amdgcn_rcpf(q2),                    \
                            bf2f(xr[3]) * __builtin_amdgcn_rcpf(q3));                   \
        *(i32x2*)((ZBUF) + zwoff) = zz;                                                 \
    }

    // prologue
    DMA_B(0, Bl0)
    XLOAD(0)
    __syncthreads();          // ekl staged + B(0) drained
    ZBUILD(z0, 0, 0)
    XLOAD(1)
    __syncthreads();          // z(0) visible

    f32x4 acc[4][2] = {};

    // STEP: C8, P1 (prefetch z/B for kc+1), P2 (xload kc+2), EKROW for ZBUILD(kc+1)
    #define STEP(C8, P1, P2, EKROW) {                                                   \
        short* zcur = ((C8) & 1) ? z1 : z0;                                             \
        short* znxt = ((C8) & 1) ? z0 : z1;                                             \
        short* bcur = ((C8) & 1) ? Bl1 : Bl0;                                           \
        short* bnxt = ((C8) & 1) ? Bl0 : Bl1;                                           \
        if (P1) {                                                                       \
            DMA_B(k3 * 8 + (C8) + 1, bnxt)                                              \
            ZBUILD(znxt, EKROW, ((C8) + 1) & 7)                                         \
        }                                                                               \
        if (P2) XLOAD(k3 * 8 + (C8) + 2)                                                \
        bf16x8 afr[4], bfr[2];                                                          \
        _Pragma("unroll")                                                               \
        for (int mt = 0; mt < 4; ++mt)                                                  \
            afr[mt] = *(const bf16x8*)(zcur + mt * 512 + lane * 8);                     \
        bfr[0] = *(const bf16x8*)(bcur + (wave * 2 + 0) * 512 + lane * 8);              \
        bfr[1] = *(const bf16x8*)(bcur + (wave * 2 + 1) * 512 + lane * 8);              \
        __builtin_amdgcn_s_setprio(1);                                                  \
        _Pragma("unroll")                                                               \
        for (int mt = 0; mt < 4; ++mt) {                                                \
            acc[mt][0] = __builtin_amdgcn_mfma_f32_16x16x32_bf16(afr[mt], bfr[0], acc[mt][0], 0, 0, 0); \
            acc[mt][1] = __builtin_amdgcn_mfma_f32_16x16x32_bf16(afr[mt], bfr[1], acc[mt][1], 0, 0, 0); \
        }                                                                               \
        __builtin_amdgcn_s_setprio(0);                                                  \
        __syncthreads();                                                                \
    }

    for (int k3 = 0; k3 < 8; ++k3) {
        STEP(0, 1, 1, k3) STEP(1, 1, 1, k3) STEP(2, 1, 1, k3) STEP(3, 1, 1, k3)
        STEP(4, 1, 1, k3) STEP(5, 1, 1, k3) STEP(6, 1, 1, k3) STEP(7, 1, 1, k3 + 1)
    }
    {   // k3 = 8 tail: kc = 64+C8; P1 while kc<71 (C8<7), P2 while kc<70 (C8<6)
        const int k3 = 8;
        STEP(0, 1, 1, k3) STEP(1, 1, 1, k3) STEP(2, 1, 1, k3) STEP(3, 1, 1, k3)
        STEP(4, 1, 1, k3) STEP(5, 1, 1, k3) STEP(6, 1, 0, k3) STEP(7, 0, 0, k3)
    }
    #undef STEP
    #undef ZBUILD
    #undef XLOAD
    #undef DMA_B

    // epilogue: o = wave*32 + nt*16 + l16 ; px = mt*16 + lg*4 + r
    #pragma unroll
    for (int mt = 0; mt < 4; ++mt)
        #pragma unroll
        for (int nt = 0; nt < 2; ++nt) {
            int o = wave * 32 + nt * 16 + l16;
            float* d = out + (((size_t)b * 256 + o) * 64 + h) * 64 + mt * 16 + lg * 4;
            *(f32x4*)d = acc[mt][nt];
        }
}

// ---------------- launcher ----------------
extern "C" void kernel_launch(void* const* d_in, const int* in_sizes, int n_in,
                              void* d_out, int out_size, void* d_ws, size_t ws_size,
                              hipStream_t stream) {
    const float* x    = (const float*)d_in[0];
    const float* w_c1 = (const float*)d_in[1];
    const float* b_c1 = (const float*)d_in[2];
    const float* w_c2 = (const float*)d_in[3];
    const float* b_c2 = (const float*)d_in[4];
    const float* w_d1 = (const float*)d_in[5];
    const float* b_d1 = (const float*)d_in[6];
    const float* w_d2 = (const float*)d_in[7];
    const float* b_d2 = (const float*)d_in[8];
    const float* Wt   = (const float*)d_in[9];
    float* out = (float*)d_out;
    char* ws = (char*)d_ws;

    short* wc1f = (short*)(ws + WS_WC1F);
    short* wc2f = (short*)(ws + WS_WC2F);
    short* wd1f = (short*)(ws + WS_WD1F);
    short* Wf   = (short*)(ws + WS_WF);
    float* ekT  = (float*)(ws + WS_EKT);
    short* enF  = (short*)(ws + WS_EN);
    short* xT8  = (short*)(ws + WS_XT);

    (void)hipFuncSetAttribute((const void*)k_branch, hipFuncAttributeMaxDynamicSharedMemorySize, BR_TOTAL);
    (void)hipFuncSetAttribute((const void*)k_final,  hipFuncAttributeMaxDynamicSharedMemorySize, FN4_TOTAL);

    k_prep<<<3008, 256, 0, stream>>>(Wt, w_d1, w_c1, w_c2, Wf, wd1f, wc1f, wc2f);
    k_prep_xt<<<512, 256, 0, stream>>>(x, xT8);
    k_branch<<<512, 512, BR_TOTAL, stream>>>(xT8, b_c1, b_c2, b_d1, w_d2, b_d2, wc1f, wc2f, wd1f, enF, ekT);
    k_final<<<512, 512, FN4_TOTAL, stream>>>(xT8, Wf, enF, ekT, out);
}

// Round 19
// 106.763 us; speedup vs baseline: 2.5220x; 1.0514x over previous
//
#include <hip/hip_runtime.h>
#include <hip/hip_bf16.h>
#include <stdint.h>

// ---------------- types / helpers ----------------
typedef __attribute__((ext_vector_type(8))) short bf16x8;
typedef __attribute__((ext_vector_type(4))) short bf16x4;
typedef __attribute__((ext_vector_type(4))) float f32x4;
typedef __attribute__((ext_vector_type(4))) int   i32x4;
typedef __attribute__((ext_vector_type(2))) int   i32x2;

#define DEV static __device__ __forceinline__

DEV float bf2f(short s) {
    unsigned u = ((unsigned)(unsigned short)s) << 16;
    return __builtin_bit_cast(float, u);
}
DEV short f2bf(float f) {  // RNE (software; prep paths)
    unsigned u = __builtin_bit_cast(unsigned, f);
    unsigned r = u + 0x7fffu + ((u >> 16) & 1u);
    return (short)(r >> 16);
}
DEV unsigned cvt_pk_bf16(float lo, float hi) {  // single HW instr
    unsigned r;
    asm("v_cvt_pk_bf16_f32 %0, %1, %2" : "=v"(r) : "v"(lo), "v"(hi));
    return r;
}

// problem constants
#define PTOT 32768
#define NEXP2 (-2.885390081777927f)   // -2*log2(e)

// ws byte offsets
#define WS_WC1F 0          // wc1f: 16384 shorts
#define WS_WC2F 32768      // wc2f: 16384 shorts
#define WS_WD1F 65536      // wd1f: 147456 shorts
#define WS_WF   360448     // Wf:   589824 shorts
#define WS_EKT  1540096
#define WS_EN   2719744    // enF: 16.8 MB
#define WS_XT   19496960   // xT8: 8*66*32*66*8 bf16 = 17842176 B ; total ~37.3 MB

// ---------------- merged prep: weights (blocks 0..3007) + padded x (blocks 3008..3519) ----
// Weights -> fragment-major (wave's MFMA B-fragment = contiguous 1KB).
// xT8[b][hp][np][wp][8] bf16 : hp,wp in [0,66) (borders zero), np = n>>3.
__global__ __launch_bounds__(256) void k_prep_all(const float* __restrict__ W, const float* __restrict__ w_d1,
                                              const float* __restrict__ w_c1, const float* __restrict__ w_c2,
                                              const float* __restrict__ x,
                                              short* __restrict__ Wf, short* __restrict__ wd1f,
                                              short* __restrict__ wc1f, short* __restrict__ wc2f,
                                              short* __restrict__ xT8) {
    __shared__ short t[64 * 74];
    const int tid = threadIdx.x;
    if (blockIdx.x < 3008) {
        int tt = blockIdx.x * 256 + tid;
        if (tt < 589824) {
            int i = tt & 7, lane = (tt >> 3) & 63, ot = (tt >> 9) & 15, kt = tt >> 13;   // kt < 72
            int o = ot * 16 + (lane & 15);
            int n = (kt & 7) * 32 + (lane >> 4) * 8 + i;
            Wf[tt] = f2bf(2.0f * W[o * 2304 + n * 9 + (kt >> 3)]);
        } else if (tt < 589824 + 147456) {
            int t2 = tt - 589824;
            int i = t2 & 7, lane = (t2 >> 3) & 63, wv = (t2 >> 9) & 3, kc = t2 >> 11; // kc < 72
            int m = wv * 16 + (lane & 15);
            int n = (kc & 7) * 32 + (lane >> 4) * 8 + i;
            wd1f[t2] = f2bf(w_d1[m * 2304 + n * 9 + (kc >> 3)]);
        } else if (tt < 589824 + 147456 + 16384) {
            int t3 = tt - (589824 + 147456);
            int i = t3 & 7, lane = (t3 >> 3) & 63, wv = (t3 >> 9) & 3, s = t3 >> 11;  // s < 8
            int m = wv * 16 + (lane & 15);
            int n = s * 32 + (lane >> 4) * 8 + i;
            wc1f[t3] = f2bf(w_c1[m * 256 + n]);
        } else if (tt < 589824 + 147456 + 32768) {
            int t4 = tt - (589824 + 147456 + 16384);
            int i = t4 & 7, lane = (t4 >> 3) & 63, ot = (t4 >> 9) & 15, s = t4 >> 13; // s < 2
            int o = ot * 16 + (lane & 15);
            int kk = s * 32 + (lane >> 4) * 8 + i;
            wc2f[t4] = f2bf(w_c2[o * 64 + kk]);
        }
        return;
    }
    const int bid = blockIdx.x - 3008;                        // 0..511
    const int rw = ((bid & 7) << 6) + (bid >> 3);
    const int b = rw >> 6, hr = rw & 63;
    const int hp = hr + 1;
    #define XI(HP, NP, WP) ((((size_t)(b) * 66 + (HP)) * 32 + (NP)) * 66 + (WP)) * 8
    if (tid < 64) {   // zero wp borders for this row
        int np = tid & 31, wp = (tid & 32) ? 65 : 0;
        *(i32x4*)(xT8 + XI(hp, np, wp)) = i32x4{0, 0, 0, 0};
    }
    if (hr == 0) {    // zero full hp=0,65 planes for this b
        for (int i = tid; i < 2 * 32 * 66; i += 256) {
            int pl = (i >= 32 * 66) ? 65 : 0;
            int rem = (i >= 32 * 66) ? i - 32 * 66 : i;
            int np = rem / 66, wp = rem - np * 66;
            *(i32x4*)(xT8 + XI(pl, np, wp)) = i32x4{0, 0, 0, 0};
        }
    }
    const int dn = tid >> 6, w = tid & 63;
    for (int p = 0; p < 4; ++p) {
        __syncthreads();
        #pragma unroll
        for (int jj = 0; jj < 16; ++jj) {
            int n = p * 64 + dn * 16 + jj;
            t[w * 74 + dn * 16 + jj] = f2bf(x[(((size_t)(b * 256 + n) * 64) + hr) * 64 + w]);
        }
        __syncthreads();
        #pragma unroll
        for (int q = 0; q < 2; ++q) {
            int nl = q * 4 + dn;
            *(bf16x8*)(xT8 + XI(hp, p * 8 + nl, w + 1)) = *(const bf16x8*)(t + w * 74 + nl * 8);
        }
    }
    #undef XI
}

// ---------------- branch kernel: enF (= e^{-2c}) and ekT (= e^{-2d}) ----------------
// enF layout per 64px row-block: [8 n0c][4 n8][64 px][8] (16B lane-contiguous for k_final).
#define BR_YD_OFF  9216
#define BR_ENT_OFF (BR_YD_OFF + 17152)
#define BR_TOTAL   (BR_ENT_OFF + 33792)   // 60160

__global__ __launch_bounds__(512, 4) void k_branch(const short* __restrict__ xT8,
        const float* __restrict__ b_c1, const float* __restrict__ b_c2,
        const float* __restrict__ b_d1, const float* __restrict__ w_d2, const float* __restrict__ b_d2,
        const short* __restrict__ wc1f, const short* __restrict__ wc2f, const short* __restrict__ wd1f,
        short* __restrict__ enF, float* __restrict__ ekT) {
    extern __shared__ char smem[];
    short* yc  = (short*)smem;
    float* ydl = (float*)(smem + BR_YD_OFF);
    short* ent = (short*)(smem + BR_ENT_OFF);

    const int rw = ((blockIdx.x & 7) << 6) + (blockIdx.x >> 3);  // XCD x <- batch x
    const int b = rw >> 6, h = rw & 63;
    const int p0 = rw << 6;
    const int tid = threadIdx.x;
    const int lane = tid & 63, wave = tid >> 6;
    const int l16 = lane & 15, lg = lane >> 4;
    const int wn = wave & 3, wm = wave >> 2;   // 2 (M) x 4 (N)
    const int cm = wn * 16 + l16;
    const size_t b66h = (size_t)(b * 66 + h);
    const int wcol = wm * 32 + l16;

    #define CONV_A(DST, KC) {                                                           \
        int k9_ = (KC) >> 3;                                                            \
        int kh_ = (k9_ * 11) >> 5, kw_ = k9_ - 3 * kh_;                                 \
        const short* xa_ = xT8 + (((b66h + kh_) * 32 + ((KC) & 7) * 4 + lg) * 66        \
                                  + wcol + kw_) * 8;                                    \
        DST[0] = *(const bf16x8*)(xa_);                                                 \
        DST[1] = *(const bf16x8*)(xa_ + 128);                                           \
    }

    // ---- GEMM1: yc = relu(x . w_c1^T + b_c1)
    {
        f32x4 acc[2] = {};
        const short* wp_ = wc1f + wn * 512 + lane * 8;
        const short* xg1 = xT8 + (((b66h + 1) * 32 + lg) * 66 + wcol + 1) * 8;  // + s*2112
        bf16x8 bcur = *(const bf16x8*)(wp_);
        bf16x8 a0 = *(const bf16x8*)(xg1), a1 = *(const bf16x8*)(xg1 + 128);
        #pragma unroll
        for (int s = 0; s < 8; ++s) {
            bf16x8 bc = bcur, c0 = a0, c1 = a1;
            if (s < 7) {
                bcur = *(const bf16x8*)(wp_ + (s + 1) * 2048);
                a0 = *(const bf16x8*)(xg1 + (s + 1) * 2112);
                a1 = *(const bf16x8*)(xg1 + (s + 1) * 2112 + 128);
            }
            acc[0] = __builtin_amdgcn_mfma_f32_16x16x32_bf16(c0, bc, acc[0], 0, 0, 0);
            acc[1] = __builtin_amdgcn_mfma_f32_16x16x32_bf16(c1, bc, acc[1], 0, 0, 0);
        }
        float bias = b_c1[cm];
        #pragma unroll
        for (int mt = 0; mt < 2; ++mt)
            #pragma unroll
            for (int r = 0; r < 4; ++r) {
                int px = wm * 32 + mt * 16 + lg * 4 + r;
                float v = acc[mt][r] + bias;
                yc[px * 72 + cm] = f2bf(v > 0.f ? v : 0.f);
            }
    }

    // ---- conv GEMM: yd = relu(conv3x3 + b_d1)
    {
        f32x4 acc[2] = {};
        const short* wp_ = wd1f + wn * 512 + lane * 8;   // kc stride 2048
        bf16x8 b0 = *(const bf16x8*)(wp_);
        bf16x8 b1 = *(const bf16x8*)(wp_ + 2048);
        bf16x8 b2 = *(const bf16x8*)(wp_ + 4096);
        bf16x8 aA[2], aB[2], aC[2];
        CONV_A(aA, 0) CONV_A(aB, 1) CONV_A(aC, 2)
        for (int kc = 0; kc < 72; kc += 3) {
            {
                bf16x8 c0 = aA[0], c1 = aA[1], bc = b0;
                int cn = (kc + 3 < 72) ? kc + 3 : 71;
                CONV_A(aA, cn)
                b0 = *(const bf16x8*)(wp_ + cn * 2048);
                acc[0] = __builtin_amdgcn_mfma_f32_16x16x32_bf16(c0, bc, acc[0], 0, 0, 0);
                acc[1] = __builtin_amdgcn_mfma_f32_16x16x32_bf16(c1, bc, acc[1], 0, 0, 0);
            }
            {
                bf16x8 c0 = aB[0], c1 = aB[1], bc = b1;
                int cn = (kc + 4 < 72) ? kc + 4 : 71;
                CONV_A(aB, cn)
                b1 = *(const bf16x8*)(wp_ + cn * 2048);
                acc[0] = __builtin_amdgcn_mfma_f32_16x16x32_bf16(c0, bc, acc[0], 0, 0, 0);
                acc[1] = __builtin_amdgcn_mfma_f32_16x16x32_bf16(c1, bc, acc[1], 0, 0, 0);
            }
            {
                bf16x8 c0 = aC[0], c1 = aC[1], bc = b2;
                int cn = (kc + 5 < 72) ? kc + 5 : 71;
                CONV_A(aC, cn)
                b2 = *(const bf16x8*)(wp_ + cn * 2048);
                acc[0] = __builtin_amdgcn_mfma_f32_16x16x32_bf16(c0, bc, acc[0], 0, 0, 0);
                acc[1] = __builtin_amdgcn_mfma_f32_16x16x32_bf16(c1, bc, acc[1], 0, 0, 0);
            }
        }
        float bias = b_d1[cm];
        #pragma unroll
        for (int mt = 0; mt < 2; ++mt)
            #pragma unroll
            for (int r = 0; r < 4; ++r) {
                int px = wm * 32 + mt * 16 + lg * 4 + r;
                float v = acc[mt][r] + bias;
                ydl[px * 67 + cm] = v > 0.f ? v : 0.f;
            }
    }
    #undef CONV_A
    __syncthreads();   // yc + ydl ready

    // ---- GEMM2 ; ent = exp(-2c)
    {
        f32x4 acc[2][4] = {};
        #pragma unroll
        for (int s = 0; s < 2; ++s) {
            int k0 = s * 32;
            bf16x8 afr[2], bfr[4];
            #pragma unroll
            for (int mt = 0; mt < 2; ++mt)
                afr[mt] = *(const bf16x8*)(yc + (wm * 32 + mt * 16 + l16) * 72 + k0 + lg * 8);
            #pragma unroll
            for (int nt = 0; nt < 4; ++nt)
                bfr[nt] = *(const bf16x8*)(wc2f + s * 8192 + (wn * 4 + nt) * 512 + lane * 8);
            #pragma unroll
            for (int mt = 0; mt < 2; ++mt)
                #pragma unroll
                for (int nt = 0; nt < 4; ++nt)
                    acc[mt][nt] = __builtin_amdgcn_mfma_f32_16x16x32_bf16(afr[mt], bfr[nt], acc[mt][nt], 0, 0, 0);
        }
        #pragma unroll
        for (int nt = 0; nt < 4; ++nt) {
            int nc = wn * 64 + nt * 16 + l16;
            float bias = b_c2[nc];
            #pragma unroll
            for (int mt = 0; mt < 2; ++mt)
                #pragma unroll
                for (int r = 0; r < 4; ++r) {
                    int px = wm * 32 + mt * 16 + lg * 4 + r;
                    float cv = acc[mt][nt][r] + bias;
                    ent[px * 264 + nc] = f2bf(exp2f(NEXP2 * cv));
                }
        }
    }

    // ---- d / ekT
    for (int t = tid; t < 576; t += 512) {
        int k = t >> 6, px = t & 63;
        float sum = b_d2[k];
        const float* yr = ydl + px * 67;
        const float* wr = w_d2 + k * 64;
        #pragma unroll 8
        for (int m = 0; m < 64; ++m) sum += yr[m] * wr[m];
        ekT[(size_t)k * PTOT + p0 + px] = exp2f(NEXP2 * sum);
    }
    __syncthreads();   // ent ready

    // ---- enF store: [8 n0c][4 n8][64 px][8], lane-contiguous 16B
    for (int i = tid; i < 2048; i += 512) {
        int px = i & 63, seg = i >> 6;   // seg = n>>3, 0..31
        *(bf16x8*)(enF + (size_t)p0 * 256 + (seg >> 2) * 2048 + (seg & 3) * 512 + px * 8)
            = *(const bf16x8*)(ent + px * 264 + seg * 8);
    }
}

// ---------------- final kernel: merged-o K-loop, 8 waves, reg-prefetched B ----------------
// 512 blocks x (64px x 256o), 512 thr (8 waves), acc[4][2]/wave.
// B is wave-PRIVATE (o-slices disjoint) -> no LDS staging: direct 2-deep register
// prefetch from L2-resident fragment-major Wf (parity-keyed regs, compile-time).
// LDS = z double-buffer + ekl only (10.5 KB); barrier guards only the z-tile.
#define FN5_Z1    4096
#define FN5_EKL   8192
#define FN5_TOTAL 10496

__global__ __launch_bounds__(512, 4) void k_final(const short* __restrict__ xT8,
        const short* __restrict__ Wf, const short* __restrict__ enF, const float* __restrict__ ekT,
        float* __restrict__ out) {
    extern __shared__ char smem[];
    short* z0  = (short*)smem;                 // [4 mt][64 lane][8]
    short* z1  = (short*)(smem + FN5_Z1);
    float* ekl = (float*)(smem + FN5_EKL);     // [9][64]

    const int rw = ((blockIdx.x & 7) << 6) + (blockIdx.x >> 3);  // 512, XCD-chunked
    const int b = rw >> 6, h = rw & 63;
    const int p0 = rw << 6;
    const int tid = threadIdx.x;
    const int lane = tid & 63, wave = tid >> 6;   // 8 waves
    const int l16 = lane & 15, lg = lane >> 4;

    for (int i = tid; i < 576; i += 512)
        ekl[i] = ekT[(size_t)(i >> 6) * PTOT + p0 + (i & 63)];

    const size_t b66h = (size_t)(b * 66 + h);
    // zbuild thread: px = lane, n = c8*32 + wave*4 + j (j=0..3)
    const int zpx = lane;
    const int wh = wave >> 1, wl = wave & 1;
    const short* xb0 = xT8 + (b66h * 32 + wh) * 528 + zpx * 8 + wl * 4;
    bf16x4 e_regs[8];
    {
        const short* enb = enF + (size_t)p0 * 256 + wh * 512 + zpx * 8 + wl * 4;
        #pragma unroll
        for (int c8 = 0; c8 < 8; ++c8) e_regs[c8] = *(const bf16x4*)(enb + c8 * 2048);
    }
    // z write slot: 8B at mt*512 + ((zpx&15) + wh*16)*8 + wl*4  (shorts)
    const int zwoff = (zpx >> 4) * 512 + ((zpx & 15) + wh * 16) * 8 + wl * 4;
    // B fragment bases (wave-private o-slice): + kc*8192 shorts per chunk
    const short* wb0 = Wf + (wave * 2 + 0) * 512 + lane * 8;
    const short* wb1 = Wf + (wave * 2 + 1) * 512 + lane * 8;

    bf16x4 xr;
    #define XLOAD(KC2) {                                                                \
        int k3_ = (KC2) >> 3, c8_ = (KC2) & 7;                                          \
        int kh_ = (k3_ * 11) >> 5, kw_ = k3_ - 3 * kh_;                                 \
        xr = *(const bf16x4*)(xb0 + kh_ * 16896 + c8_ * 2112 + kw_ * 8);                \
    }
    // EIDX must be a compile-time constant (register-resident e_regs)
    #define ZBUILD(ZBUF, EKROW, EIDX) {                                                 \
        bf16x4 er = e_regs[EIDX];                                                       \
        float ekv = ekl[(EKROW) * 64 + zpx];                                            \
        float q0 = __builtin_fmaf(ekv, bf2f(er[0]), 1.0f);                              \
        float q1 = __builtin_fmaf(ekv, bf2f(er[1]), 1.0f);                              \
        float q2 = __builtin_fmaf(ekv, bf2f(er[2]), 1.0f);                              \
        float q3 = __builtin_fmaf(ekv, bf2f(er[3]), 1.0f);                              \
        i32x2 zz;                                                                       \
        zz[0] = cvt_pk_bf16(bf2f(xr[0]) * __builtin_amdgcn_rcpf(q0),                    \
                            bf2f(xr[1]) * __builtin_amdgcn_rcpf(q1));                   \
        zz[1] = cvt_pk_bf16(bf2f(xr[2]) * __builtin_amdgcn_rcpf(q2),                    \
                            bf2f(xr[3]) * __builtin_amdgcn_rcpf(q3));                   \
        *(i32x2*)((ZBUF) + zwoff) = zz;                                                 \
    }

    // prologue: B(0) -> Be, B(1) -> Bo
    bf16x8 Be[2], Bo[2];
    Be[0] = *(const bf16x8*)(wb0);          Be[1] = *(const bf16x8*)(wb1);
    Bo[0] = *(const bf16x8*)(wb0 + 8192);   Bo[1] = *(const bf16x8*)(wb1 + 8192);
    XLOAD(0)
    __syncthreads();          // ekl staged
    ZBUILD(z0, 0, 0)
    XLOAD(1)
    __syncthreads();          // z(0) visible

    f32x4 acc[4][2] = {};

    // STEP: C8 parity keys z-buffer and B regs; P1 = prefetch z(kc+1); P2 = load (kc+2)
    #define STEP(C8, P1, P2, EKROW) {                                                   \
        short* zcur = ((C8) & 1) ? z1 : z0;                                             \
        short* znxt = ((C8) & 1) ? z0 : z1;                                             \
        bf16x8 bc0, bc1;                                                                \
        if ((C8) & 1) { bc0 = Bo[0]; bc1 = Bo[1]; } else { bc0 = Be[0]; bc1 = Be[1]; }  \
        if (P2) {  /* B(kc+2) into same-parity regs; issued early for latency cover */  \
            int kb2_ = (k3 * 8 + (C8) + 2) * 8192;                                      \
            if ((C8) & 1) { Bo[0] = *(const bf16x8*)(wb0 + kb2_);                       \
                            Bo[1] = *(const bf16x8*)(wb1 + kb2_); }                     \
            else          { Be[0] = *(const bf16x8*)(wb0 + kb2_);                       \
                            Be[1] = *(const bf16x8*)(wb1 + kb2_); }                     \
        }                                                                               \
        if (P1) ZBUILD(znxt, EKROW, ((C8) + 1) & 7)                                     \
        if (P2) XLOAD(k3 * 8 + (C8) + 2)                                                \
        bf16x8 afr[4];                                                                  \
        _Pragma("unroll")                                                               \
        for (int mt = 0; mt < 4; ++mt)                                                  \
            afr[mt] = *(const bf16x8*)(zcur + mt * 512 + lane * 8);                     \
        __builtin_amdgcn_s_setprio(1);                                                  \
        _Pragma("unroll")                                                               \
        for (int mt = 0; mt < 4; ++mt) {                                                \
            acc[mt][0] = __builtin_amdgcn_mfma_f32_16x16x32_bf16(afr[mt], bc0, acc[mt][0], 0, 0, 0); \
            acc[mt][1] = __builtin_amdgcn_mfma_f32_16x16x32_bf16(afr[mt], bc1, acc[mt][1], 0, 0, 0); \
        }                                                                               \
        __builtin_amdgcn_s_setprio(0);                                                  \
        __syncthreads();                                                                \
    }

    for (int k3 = 0; k3 < 8; ++k3) {
        STEP(0, 1, 1, k3) STEP(1, 1, 1, k3) STEP(2, 1, 1, k3) STEP(3, 1, 1, k3)
        STEP(4, 1, 1, k3) STEP(5, 1, 1, k3) STEP(6, 1, 1, k3) STEP(7, 1, 1, k3 + 1)
    }
    {   // k3 = 8 tail: kc = 64+C8; P1 while kc<71 (C8<7), P2 while kc<70 (C8<6)
        const int k3 = 8;
        STEP(0, 1, 1, k3) STEP(1, 1, 1, k3) STEP(2, 1, 1, k3) STEP(3, 1, 1, k3)
        STEP(4, 1, 1, k3) STEP(5, 1, 1, k3) STEP(6, 1, 0, k3) STEP(7, 0, 0, k3)
    }
    #undef STEP
    #undef ZBUILD
    #undef XLOAD

    // epilogue: o = wave*32 + nt*16 + l16 ; px = mt*16 + lg*4 + r
    #pragma unroll
    for (int mt = 0; mt < 4; ++mt)
        #pragma unroll
        for (int nt = 0; nt < 2; ++nt) {
            int o = wave * 32 + nt * 16 + l16;
            float* d = out + (((size_t)b * 256 + o) * 64 + h) * 64 + mt * 16 + lg * 4;
            *(f32x4*)d = acc[mt][nt];
        }
}

// ---------------- launcher ----------------
extern "C" void kernel_launch(void* const* d_in, const int* in_sizes, int n_in,
                              void* d_out, int out_size, void* d_ws, size_t ws_size,
                              hipStream_t stream) {
    const float* x    = (const float*)d_in[0];
    const float* w_c1 = (const float*)d_in[1];
    const float* b_c1 = (const float*)d_in[2];
    const float* w_c2 = (const float*)d_in[3];
    const float* b_c2 = (const float*)d_in[4];
    const float* w_d1 = (const float*)d_in[5];
    const float* b_d1 = (const float*)d_in[6];
    const float* w_d2 = (const float*)d_in[7];
    const float* b_d2 = (const float*)d_in[8];
    const float* Wt   = (const float*)d_in[9];
    float* out = (float*)d_out;
    char* ws = (char*)d_ws;

    short* wc1f = (short*)(ws + WS_WC1F);
    short* wc2f = (short*)(ws + WS_WC2F);
    short* wd1f = (short*)(ws + WS_WD1F);
    short* Wf   = (short*)(ws + WS_WF);
    float* ekT  = (float*)(ws + WS_EKT);
    short* enF  = (short*)(ws + WS_EN);
    short* xT8  = (short*)(ws + WS_XT);

    (void)hipFuncSetAttribute((const void*)k_branch, hipFuncAttributeMaxDynamicSharedMemorySize, BR_TOTAL);
    (void)hipFuncSetAttribute((const void*)k_final,  hipFuncAttributeMaxDynamicSharedMemorySize, FN5_TOTAL);

    k_prep_all<<<3520, 256, 0, stream>>>(Wt, w_d1, w_c1, w_c2, x, Wf, wd1f, wc1f, wc2f, xT8);
    k_branch<<<512, 512, BR_TOTAL, stream>>>(xT8, b_c1, b_c2, b_d1, w_d2, b_d2, wc1f, wc2f, wd1f, enF, ekT);
    k_final<<<512, 512, FN5_TOTAL, stream>>>(xT8, Wf, enF, ekT, out);
}

// Round 20
// 103.839 us; speedup vs baseline: 2.5930x; 1.0282x over previous
//
#include <hip/hip_runtime.h>
#include <hip/hip_bf16.h>
#include <stdint.h>

// ---------------- types / helpers ----------------
typedef __attribute__((ext_vector_type(8))) short bf16x8;
typedef __attribute__((ext_vector_type(4))) short bf16x4;
typedef __attribute__((ext_vector_type(4))) float f32x4;
typedef __attribute__((ext_vector_type(4))) int   i32x4;
typedef __attribute__((ext_vector_type(2))) int   i32x2;

#define DEV static __device__ __forceinline__

DEV float bf2f(short s) {
    unsigned u = ((unsigned)(unsigned short)s) << 16;
    return __builtin_bit_cast(float, u);
}
DEV short f2bf(float f) {  // RNE (software; prep paths)
    unsigned u = __builtin_bit_cast(unsigned, f);
    unsigned r = u + 0x7fffu + ((u >> 16) & 1u);
    return (short)(r >> 16);
}
DEV unsigned cvt_pk_bf16(float lo, float hi) {  // single HW instr
    unsigned r;
    asm("v_cvt_pk_bf16_f32 %0, %1, %2" : "=v"(r) : "v"(lo), "v"(hi));
    return r;
}

// problem constants
#define PTOT 32768
#define NEXP2 (-2.885390081777927f)   // -2*log2(e)

// ws byte offsets
#define WS_WC1F 0          // wc1f: 16384 shorts
#define WS_WC2F 32768      // wc2f: 16384 shorts
#define WS_WD1F 65536      // wd1f: 147456 shorts
#define WS_WF   360448     // Wf:   589824 shorts
#define WS_EKT  1540096
#define WS_EN   2719744    // enF: 16.8 MB
#define WS_XT   19496960   // xT8: 8*66*32*66*8 bf16 = 17842176 B ; total ~37.3 MB

// ---------------- merged prep: weights (blocks 0..3007) + padded x (blocks 3008..3519) ----
__global__ __launch_bounds__(256) void k_prep_all(const float* __restrict__ W, const float* __restrict__ w_d1,
                                              const float* __restrict__ w_c1, const float* __restrict__ w_c2,
                                              const float* __restrict__ x,
                                              short* __restrict__ Wf, short* __restrict__ wd1f,
                                              short* __restrict__ wc1f, short* __restrict__ wc2f,
                                              short* __restrict__ xT8) {
    __shared__ short t[64 * 74];
    const int tid = threadIdx.x;
    if (blockIdx.x < 3008) {
        int tt = blockIdx.x * 256 + tid;
        if (tt < 589824) {
            int i = tt & 7, lane = (tt >> 3) & 63, ot = (tt >> 9) & 15, kt = tt >> 13;   // kt < 72
            int o = ot * 16 + (lane & 15);
            int n = (kt & 7) * 32 + (lane >> 4) * 8 + i;
            Wf[tt] = f2bf(2.0f * W[o * 2304 + n * 9 + (kt >> 3)]);
        } else if (tt < 589824 + 147456) {
            int t2 = tt - 589824;
            int i = t2 & 7, lane = (t2 >> 3) & 63, wv = (t2 >> 9) & 3, kc = t2 >> 11; // kc < 72
            int m = wv * 16 + (lane & 15);
            int n = (kc & 7) * 32 + (lane >> 4) * 8 + i;
            wd1f[t2] = f2bf(w_d1[m * 2304 + n * 9 + (kc >> 3)]);
        } else if (tt < 589824 + 147456 + 16384) {
            int t3 = tt - (589824 + 147456);
            int i = t3 & 7, lane = (t3 >> 3) & 63, wv = (t3 >> 9) & 3, s = t3 >> 11;  // s < 8
            int m = wv * 16 + (lane & 15);
            int n = s * 32 + (lane >> 4) * 8 + i;
            wc1f[t3] = f2bf(w_c1[m * 256 + n]);
        } else if (tt < 589824 + 147456 + 32768) {
            int t4 = tt - (589824 + 147456 + 16384);
            int i = t4 & 7, lane = (t4 >> 3) & 63, ot = (t4 >> 9) & 15, s = t4 >> 13; // s < 2
            int o = ot * 16 + (lane & 15);
            int kk = s * 32 + (lane >> 4) * 8 + i;
            wc2f[t4] = f2bf(w_c2[o * 64 + kk]);
        }
        return;
    }
    const int bid = blockIdx.x - 3008;                        // 0..511
    const int rw = ((bid & 7) << 6) + (bid >> 3);
    const int b = rw >> 6, hr = rw & 63;
    const int hp = hr + 1;
    #define XI(HP, NP, WP) ((((size_t)(b) * 66 + (HP)) * 32 + (NP)) * 66 + (WP)) * 8
    if (tid < 64) {   // zero wp borders for this row
        int np = tid & 31, wp = (tid & 32) ? 65 : 0;
        *(i32x4*)(xT8 + XI(hp, np, wp)) = i32x4{0, 0, 0, 0};
    }
    if (hr == 0) {    // zero full hp=0,65 planes for this b
        for (int i = tid; i < 2 * 32 * 66; i += 256) {
            int pl = (i >= 32 * 66) ? 65 : 0;
            int rem = (i >= 32 * 66) ? i - 32 * 66 : i;
            int np = rem / 66, wp = rem - np * 66;
            *(i32x4*)(xT8 + XI(pl, np, wp)) = i32x4{0, 0, 0, 0};
        }
    }
    const int dn = tid >> 6, w = tid & 63;
    for (int p = 0; p < 4; ++p) {
        __syncthreads();
        #pragma unroll
        for (int jj = 0; jj < 16; ++jj) {
            int n = p * 64 + dn * 16 + jj;
            t[w * 74 + dn * 16 + jj] = f2bf(x[(((size_t)(b * 256 + n) * 64) + hr) * 64 + w]);
        }
        __syncthreads();
        #pragma unroll
        for (int q = 0; q < 2; ++q) {
            int nl = q * 4 + dn;
            *(bf16x8*)(xT8 + XI(hp, p * 8 + nl, w + 1)) = *(const bf16x8*)(t + w * 74 + nl * 8);
        }
    }
    #undef XI
}

// ---------------- branch kernel: enF (= e^{-2c}) and ekT (= e^{-2d}) ----------------
#define BR_YD_OFF  9216
#define BR_ENT_OFF (BR_YD_OFF + 17152)
#define BR_TOTAL   (BR_ENT_OFF + 33792)   // 60160

__global__ __launch_bounds__(512, 4) void k_branch(const short* __restrict__ xT8,
        const float* __restrict__ b_c1, const float* __restrict__ b_c2,
        const float* __restrict__ b_d1, const float* __restrict__ w_d2, const float* __restrict__ b_d2,
        const short* __restrict__ wc1f, const short* __restrict__ wc2f, const short* __restrict__ wd1f,
        short* __restrict__ enF, float* __restrict__ ekT) {
    extern __shared__ char smem[];
    short* yc  = (short*)smem;
    float* ydl = (float*)(smem + BR_YD_OFF);
    short* ent = (short*)(smem + BR_ENT_OFF);

    const int rw = ((blockIdx.x & 7) << 6) + (blockIdx.x >> 3);  // XCD x <- batch x
    const int b = rw >> 6, h = rw & 63;
    const int p0 = rw << 6;
    const int tid = threadIdx.x;
    const int lane = tid & 63, wave = tid >> 6;
    const int l16 = lane & 15, lg = lane >> 4;
    const int wn = wave & 3, wm = wave >> 2;   // 2 (M) x 4 (N)
    const int cm = wn * 16 + l16;
    const size_t b66h = (size_t)(b * 66 + h);
    const int wcol = wm * 32 + l16;

    #define CONV_A(DST, KC) {                                                           \
        int k9_ = (KC) >> 3;                                                            \
        int kh_ = (k9_ * 11) >> 5, kw_ = k9_ - 3 * kh_;                                 \
        const short* xa_ = xT8 + (((b66h + kh_) * 32 + ((KC) & 7) * 4 + lg) * 66        \
                                  + wcol + kw_) * 8;                                    \
        DST[0] = *(const bf16x8*)(xa_);                                                 \
        DST[1] = *(const bf16x8*)(xa_ + 128);                                           \
    }

    // ---- GEMM1: yc = relu(x . w_c1^T + b_c1)
    {
        f32x4 acc[2] = {};
        const short* wp_ = wc1f + wn * 512 + lane * 8;
        const short* xg1 = xT8 + (((b66h + 1) * 32 + lg) * 66 + wcol + 1) * 8;  // + s*2112
        bf16x8 bcur = *(const bf16x8*)(wp_);
        bf16x8 a0 = *(const bf16x8*)(xg1), a1 = *(const bf16x8*)(xg1 + 128);
        #pragma unroll
        for (int s = 0; s < 8; ++s) {
            bf16x8 bc = bcur, c0 = a0, c1 = a1;
            if (s < 7) {
                bcur = *(const bf16x8*)(wp_ + (s + 1) * 2048);
                a0 = *(const bf16x8*)(xg1 + (s + 1) * 2112);
                a1 = *(const bf16x8*)(xg1 + (s + 1) * 2112 + 128);
            }
            acc[0] = __builtin_amdgcn_mfma_f32_16x16x32_bf16(c0, bc, acc[0], 0, 0, 0);
            acc[1] = __builtin_amdgcn_mfma_f32_16x16x32_bf16(c1, bc, acc[1], 0, 0, 0);
        }
        float bias = b_c1[cm];
        #pragma unroll
        for (int mt = 0; mt < 2; ++mt)
            #pragma unroll
            for (int r = 0; r < 4; ++r) {
                int px = wm * 32 + mt * 16 + lg * 4 + r;
                float v = acc[mt][r] + bias;
                yc[px * 72 + cm] = f2bf(v > 0.f ? v : 0.f);
            }
    }

    // ---- conv GEMM: yd = relu(conv3x3 + b_d1)
    {
        f32x4 acc[2] = {};
        const short* wp_ = wd1f + wn * 512 + lane * 8;   // kc stride 2048
        bf16x8 b0 = *(const bf16x8*)(wp_);
        bf16x8 b1 = *(const bf16x8*)(wp_ + 2048);
        bf16x8 b2 = *(const bf16x8*)(wp_ + 4096);
        bf16x8 aA[2], aB[2], aC[2];
        CONV_A(aA, 0) CONV_A(aB, 1) CONV_A(aC, 2)
        for (int kc = 0; kc < 72; kc += 3) {
            {
                bf16x8 c0 = aA[0], c1 = aA[1], bc = b0;
                int cn = (kc + 3 < 72) ? kc + 3 : 71;
                CONV_A(aA, cn)
                b0 = *(const bf16x8*)(wp_ + cn * 2048);
                acc[0] = __builtin_amdgcn_mfma_f32_16x16x32_bf16(c0, bc, acc[0], 0, 0, 0);
                acc[1] = __builtin_amdgcn_mfma_f32_16x16x32_bf16(c1, bc, acc[1], 0, 0, 0);
            }
            {
                bf16x8 c0 = aB[0], c1 = aB[1], bc = b1;
                int cn = (kc + 4 < 72) ? kc + 4 : 71;
                CONV_A(aB, cn)
                b1 = *(const bf16x8*)(wp_ + cn * 2048);
                acc[0] = __builtin_amdgcn_mfma_f32_16x16x32_bf16(c0, bc, acc[0], 0, 0, 0);
                acc[1] = __builtin_amdgcn_mfma_f32_16x16x32_bf16(c1, bc, acc[1], 0, 0, 0);
            }
            {
                bf16x8 c0 = aC[0], c1 = aC[1], bc = b2;
                int cn = (kc + 5 < 72) ? kc + 5 : 71;
                CONV_A(aC, cn)
                b2 = *(const bf16x8*)(wp_ + cn * 2048);
                acc[0] = __builtin_amdgcn_mfma_f32_16x16x32_bf16(c0, bc, acc[0], 0, 0, 0);
                acc[1] = __builtin_amdgcn_mfma_f32_16x16x32_bf16(c1, bc, acc[1], 0, 0, 0);
            }
        }
        float bias = b_d1[cm];
        #pragma unroll
        for (int mt = 0; mt < 2; ++mt)
            #pragma unroll
            for (int r = 0; r < 4; ++r) {
                int px = wm * 32 + mt * 16 + lg * 4 + r;
                float v = acc[mt][r] + bias;
                ydl[px * 67 + cm] = v > 0.f ? v : 0.f;
            }
    }
    #undef CONV_A
    __syncthreads();   // yc + ydl ready

    // ---- GEMM2 ; ent = exp(-2c)
    {
        f32x4 acc[2][4] = {};
        #pragma unroll
        for (int s = 0; s < 2; ++s) {
            int k0 = s * 32;
            bf16x8 afr[2], bfr[4];
            #pragma unroll
            for (int mt = 0; mt < 2; ++mt)
                afr[mt] = *(const bf16x8*)(yc + (wm * 32 + mt * 16 + l16) * 72 + k0 + lg * 8);
            #pragma unroll
            for (int nt = 0; nt < 4; ++nt)
                bfr[nt] = *(const bf16x8*)(wc2f + s * 8192 + (wn * 4 + nt) * 512 + lane * 8);
            #pragma unroll
            for (int mt = 0; mt < 2; ++mt)
                #pragma unroll
                for (int nt = 0; nt < 4; ++nt)
                    acc[mt][nt] = __builtin_amdgcn_mfma_f32_16x16x32_bf16(afr[mt], bfr[nt], acc[mt][nt], 0, 0, 0);
        }
        #pragma unroll
        for (int nt = 0; nt < 4; ++nt) {
            int nc = wn * 64 + nt * 16 + l16;
            float bias = b_c2[nc];
            #pragma unroll
            for (int mt = 0; mt < 2; ++mt)
                #pragma unroll
                for (int r = 0; r < 4; ++r) {
                    int px = wm * 32 + mt * 16 + lg * 4 + r;
                    float cv = acc[mt][nt][r] + bias;
                    ent[px * 264 + nc] = f2bf(exp2f(NEXP2 * cv));
                }
        }
    }

    // ---- d / ekT
    for (int t = tid; t < 576; t += 512) {
        int k = t >> 6, px = t & 63;
        float sum = b_d2[k];
        const float* yr = ydl + px * 67;
        const float* wr = w_d2 + k * 64;
        #pragma unroll 8
        for (int m = 0; m < 64; ++m) sum += yr[m] * wr[m];
        ekT[(size_t)k * PTOT + p0 + px] = exp2f(NEXP2 * sum);
    }
    __syncthreads();   // ent ready

    // ---- enF store: [8 n0c][4 n8][64 px][8], lane-contiguous 16B
    for (int i = tid; i < 2048; i += 512) {
        int px = i & 63, seg = i >> 6;   // seg = n>>3, 0..31
        *(bf16x8*)(enF + (size_t)p0 * 256 + (seg >> 2) * 2048 + (seg & 3) * 512 + px * 8)
            = *(const bf16x8*)(ent + px * 264 + seg * 8);
    }
}

// ---------------- final kernel: 2-step phases, quad-buffered z, reg B ----------------
// 512 blocks x (64px x 256o), 512 thr (8 waves), acc[4][2]/wave.
// 36 phases (barrier per 2 K-steps): phase kc reads z[kc&3], z[(kc+1)&3];
// builds z[(kc+2)&3], z[(kc+3)&3]; B/x pipelines 2 steps ahead. All buffer,
// e_regs indices compile-time (rule #20). LDS 18.7 KB.
#define FN6_EKL   16384
#define FN6_TOTAL 18688

__global__ __launch_bounds__(512, 4) void k_final(const short* __restrict__ xT8,
        const short* __restrict__ Wf, const short* __restrict__ enF, const float* __restrict__ ekT,
        float* __restrict__ out) {
    extern __shared__ char smem[];
    short* zq0 = (short*)smem;                 // each [4 mt][64 lane][8] = 4KB
    short* zq1 = (short*)(smem + 4096);
    short* zq2 = (short*)(smem + 8192);
    short* zq3 = (short*)(smem + 12288);
    float* ekl = (float*)(smem + FN6_EKL);     // [9][64]

    const int rw = ((blockIdx.x & 7) << 6) + (blockIdx.x >> 3);  // 512, XCD-chunked
    const int b = rw >> 6, h = rw & 63;
    const int p0 = rw << 6;
    const int tid = threadIdx.x;
    const int lane = tid & 63, wave = tid >> 6;   // 8 waves
    const int l16 = lane & 15, lg = lane >> 4;

    for (int i = tid; i < 576; i += 512)
        ekl[i] = ekT[(size_t)(i >> 6) * PTOT + p0 + (i & 63)];

    const size_t b66h = (size_t)(b * 66 + h);
    const int zpx = lane;
    const int wh = wave >> 1, wl = wave & 1;
    const short* xb0 = xT8 + (b66h * 32 + wh) * 528 + zpx * 8 + wl * 4;
    bf16x4 e_regs[8];
    {
        const short* enb = enF + (size_t)p0 * 256 + wh * 512 + zpx * 8 + wl * 4;
        #pragma unroll
        for (int c8 = 0; c8 < 8; ++c8) e_regs[c8] = *(const bf16x4*)(enb + c8 * 2048);
    }
    const int zwoff = (zpx >> 4) * 512 + ((zpx & 15) + wh * 16) * 8 + wl * 4;
    const short* wb0 = Wf + (wave * 2 + 0) * 512 + lane * 8;
    const short* wb1 = Wf + (wave * 2 + 1) * 512 + lane * 8;

    #define ZQ(I) ((I) == 0 ? zq0 : (I) == 1 ? zq1 : (I) == 2 ? zq2 : zq3)

    bf16x4 xrA, xrB;
    #define XLOADA(KC2) {                                                               \
        int k3_ = (KC2) >> 3, c8_ = (KC2) & 7;                                          \
        int kh_ = (k3_ * 11) >> 5, kw_ = k3_ - 3 * kh_;                                 \
        xrA = *(const bf16x4*)(xb0 + kh_ * 16896 + c8_ * 2112 + kw_ * 8);               \
    }
    #define XLOADB(KC2) {                                                               \
        int k3_ = (KC2) >> 3, c8_ = (KC2) & 7;                                          \
        int kh_ = (k3_ * 11) >> 5, kw_ = k3_ - 3 * kh_;                                 \
        xrB = *(const bf16x4*)(xb0 + kh_ * 16896 + c8_ * 2112 + kw_ * 8);               \
    }
    #define ZBUILDX(ZBUF, EKROW, EIDX, XR) {                                            \
        bf16x4 er = e_regs[EIDX];                                                       \
        float ekv = ekl[(EKROW) * 64 + zpx];                                            \
        float q0 = __builtin_fmaf(ekv, bf2f(er[0]), 1.0f);                              \
        float q1 = __builtin_fmaf(ekv, bf2f(er[1]), 1.0f);                              \
        float q2 = __builtin_fmaf(ekv, bf2f(er[2]), 1.0f);                              \
        float q3 = __builtin_fmaf(ekv, bf2f(er[3]), 1.0f);                              \
        i32x2 zz;                                                                       \
        zz[0] = cvt_pk_bf16(bf2f(XR[0]) * __builtin_amdgcn_rcpf(q0),                    \
                            bf2f(XR[1]) * __builtin_amdgcn_rcpf(q1));                   \
        zz[1] = cvt_pk_bf16(bf2f(XR[2]) * __builtin_amdgcn_rcpf(q2),                    \
                            bf2f(XR[3]) * __builtin_amdgcn_rcpf(q3));                   \
        *(i32x2*)((ZBUF) + zwoff) = zz;                                                 \
    }

    // prologue: B(0)->Be, B(1)->Bo; x(0),x(1); build z0,z1; x(2),x(3)
    bf16x8 Be[2], Bo[2];
    Be[0] = *(const bf16x8*)(wb0);          Be[1] = *(const bf16x8*)(wb1);
    Bo[0] = *(const bf16x8*)(wb0 + 8192);   Bo[1] = *(const bf16x8*)(wb1 + 8192);
    XLOADA(0) XLOADB(1)
    __syncthreads();          // ekl staged
    ZBUILDX(zq0, 0, 0, xrA)
    ZBUILDX(zq1, 0, 1, xrB)
    XLOADA(2) XLOADB(3)
    __syncthreads();          // z0,z1 visible

    f32x4 acc[4][2] = {};

    // PHASE(C8 in {0,2,4,6}): steps kc=k3*8+C8, kc+1.
    #define PHASE(C8, P1, P2, EKR) {                                                    \
        short* zE = ZQ((C8) & 3);                                                       \
        short* zO = ZQ(((C8) + 1) & 3);                                                 \
        bf16x8 afr[4];                                                                  \
        _Pragma("unroll")                                                               \
        for (int mt = 0; mt < 4; ++mt)                                                  \
            afr[mt] = *(const bf16x8*)(zE + mt * 512 + lane * 8);                       \
        __builtin_amdgcn_s_setprio(1);                                                  \
        _Pragma("unroll")                                                               \
        for (int mt = 0; mt < 4; ++mt) {                                                \
            acc[mt][0] = __builtin_amdgcn_mfma_f32_16x16x32_bf16(afr[mt], Be[0], acc[mt][0], 0, 0, 0); \
            acc[mt][1] = __builtin_amdgcn_mfma_f32_16x16x32_bf16(afr[mt], Be[1], acc[mt][1], 0, 0, 0); \
        }                                                                               \
        __builtin_amdgcn_s_setprio(0);                                                  \
        if (P1) {                                                                       \
            int kb2_ = (k3 * 8 + (C8) + 2) * 8192;                                      \
            Be[0] = *(const bf16x8*)(wb0 + kb2_);                                       \
            Be[1] = *(const bf16x8*)(wb1 + kb2_);                                       \
            ZBUILDX(ZQ(((C8) + 2) & 3), EKR, ((C8) + 2) & 7, xrA)                       \
        }                                                                               \
        if (P2) XLOADA(k3 * 8 + (C8) + 4)                                               \
        _Pragma("unroll")                                                               \
        for (int mt = 0; mt < 4; ++mt)                                                  \
            afr[mt] = *(const bf16x8*)(zO + mt * 512 + lane * 8);                       \
        __builtin_amdgcn_s_setprio(1);                                                  \
        _Pragma("unroll")                                                               \
        for (int mt = 0; mt < 4; ++mt) {                                                \
            acc[mt][0] = __builtin_amdgcn_mfma_f32_16x16x32_bf16(afr[mt], Bo[0], acc[mt][0], 0, 0, 0); \
            acc[mt][1] = __builtin_amdgcn_mfma_f32_16x16x32_bf16(afr[mt], Bo[1], acc[mt][1], 0, 0, 0); \
        }                                                                               \
        __builtin_amdgcn_s_setprio(0);                                                  \
        if (P1) {                                                                       \
            int kb3_ = (k3 * 8 + (C8) + 3) * 8192;                                      \
            Bo[0] = *(const bf16x8*)(wb0 + kb3_);                                       \
            Bo[1] = *(const bf16x8*)(wb1 + kb3_);                                       \
            ZBUILDX(ZQ(((C8) + 3) & 3), EKR, ((C8) + 3) & 7, xrB)                       \
        }                                                                               \
        if (P2) XLOADB(k3 * 8 + (C8) + 5)                                               \
        __syncthreads();                                                                \
    }

    for (int k3 = 0; k3 < 8; ++k3) {
        PHASE(0, 1, 1, k3) PHASE(2, 1, 1, k3)
        PHASE(4, 1, 1, k3) PHASE(6, 1, 1, k3 + 1)
    }
    {   // k3 = 8 tail: phases kc = 64,66,68,70
        const int k3 = 8;
        PHASE(0, 1, 1, k3) PHASE(2, 1, 1, k3)
        PHASE(4, 1, 0, k3) PHASE(6, 0, 0, k3)
    }
    #undef PHASE
    #undef ZBUILDX
    #undef XLOADA
    #undef XLOADB
    #undef ZQ

    // epilogue: o = wave*32 + nt*16 + l16 ; px = mt*16 + lg*4 + r
    #pragma unroll
    for (int mt = 0; mt < 4; ++mt)
        #pragma unroll
        for (int nt = 0; nt < 2; ++nt) {
            int o = wave * 32 + nt * 16 + l16;
            float* d = out + (((size_t)b * 256 + o) * 64 + h) * 64 + mt * 16 + lg * 4;
            *(f32x4*)d = acc[mt][nt];
        }
}

// ---------------- launcher ----------------
extern "C" void kernel_launch(void* const* d_in, const int* in_sizes, int n_in,
                              void* d_out, int out_size, void* d_ws, size_t ws_size,
                              hipStream_t stream) {
    const float* x    = (const float*)d_in[0];
    const float* w_c1 = (const float*)d_in[1];
    const float* b_c1 = (const float*)d_in[2];
    const float* w_c2 = (const float*)d_in[3];
    const float* b_c2 = (const float*)d_in[4];
    const float* w_d1 = (const float*)d_in[5];
    const float* b_d1 = (const float*)d_in[6];
    const float* w_d2 = (const float*)d_in[7];
    const float* b_d2 = (const float*)d_in[8];
    const float* Wt   = (const float*)d_in[9];
    float* out = (float*)d_out;
    char* ws = (char*)d_ws;

    short* wc1f = (short*)(ws + WS_WC1F);
    short* wc2f = (short*)(ws + WS_WC2F);
    short* wd1f = (short*)(ws + WS_WD1F);
    short* Wf   = (short*)(ws + WS_WF);
    float* ekT  = (float*)(ws + WS_EKT);
    short* enF  = (short*)(ws + WS_EN);
    short* xT8  = (short*)(ws + WS_XT);

    (void)hipFuncSetAttribute((const void*)k_branch, hipFuncAttributeMaxDynamicSharedMemorySize, BR_TOTAL);
    (void)hipFuncSetAttribute((const void*)k_final,  hipFuncAttributeMaxDynamicSharedMemorySize, FN6_TOTAL);

    k_prep_all<<<3520, 256, 0, stream>>>(Wt, w_d1, w_c1, w_c2, x, Wf, wd1f, wc1f, wc2f, xT8);
    k_branch<<<512, 512, BR_TOTAL, stream>>>(xT8, b_c1, b_c2, b_d1, w_d2, b_d2, wc1f, wc2f, wd1f, enF, ekT);
    k_final<<<512, 512, FN6_TOTAL, stream>>>(xT8, Wf, enF, ekT, out);
}

// Round 21
// 93.141 us; speedup vs baseline: 2.8908x; 1.1149x over previous
//
#include <hip/hip_runtime.h>
#include <hip/hip_bf16.h>
#include <stdint.h>

// ---------------- types / helpers ----------------
typedef __attribute__((ext_vector_type(8))) short bf16x8;
typedef __attribute__((ext_vector_type(4))) short bf16x4;
typedef __attribute__((ext_vector_type(4))) float f32x4;
typedef __attribute__((ext_vector_type(4))) int   i32x4;
typedef __attribute__((ext_vector_type(2))) int   i32x2;

#define DEV static __device__ __forceinline__

DEV float bf2f(short s) {
    unsigned u = ((unsigned)(unsigned short)s) << 16;
    return __builtin_bit_cast(float, u);
}
DEV short f2bf(float f) {  // RNE (software; prep paths)
    unsigned u = __builtin_bit_cast(unsigned, f);
    unsigned r = u + 0x7fffu + ((u >> 16) & 1u);
    return (short)(r >> 16);
}
DEV unsigned cvt_pk_bf16(float lo, float hi) {  // single HW instr
    unsigned r;
    asm("v_cvt_pk_bf16_f32 %0, %1, %2" : "=v"(r) : "v"(lo), "v"(hi));
    return r;
}

// problem constants
#define PTOT 32768
#define NEXP2 (-2.885390081777927f)   // -2*log2(e)

// ws byte offsets
#define WS_WC1F 0          // wc1f: 16384 shorts
#define WS_WC2F 32768      // wc2f: 16384 shorts
#define WS_WD1F 65536      // wd1f: 147456 shorts
#define WS_WF   360448     // Wf:   589824 shorts
#define WS_XT   19496960   // xT8: 8*66*32*66*8 bf16 = 17842176 B

// ---------------- merged prep: weights (blocks 0..3007) + padded x (blocks 3008..3519) ----
__global__ __launch_bounds__(256) void k_prep_all(const float* __restrict__ W, const float* __restrict__ w_d1,
                                              const float* __restrict__ w_c1, const float* __restrict__ w_c2,
                                              const float* __restrict__ x,
                                              short* __restrict__ Wf, short* __restrict__ wd1f,
                                              short* __restrict__ wc1f, short* __restrict__ wc2f,
                                              short* __restrict__ xT8) {
    __shared__ short t[64 * 74];
    const int tid = threadIdx.x;
    if (blockIdx.x < 3008) {
        int tt = blockIdx.x * 256 + tid;
        if (tt < 589824) {
            int i = tt & 7, lane = (tt >> 3) & 63, ot = (tt >> 9) & 15, kt = tt >> 13;   // kt < 72
            int o = ot * 16 + (lane & 15);
            int n = (kt & 7) * 32 + (lane >> 4) * 8 + i;
            Wf[tt] = f2bf(2.0f * W[o * 2304 + n * 9 + (kt >> 3)]);
        } else if (tt < 589824 + 147456) {
            int t2 = tt - 589824;
            int i = t2 & 7, lane = (t2 >> 3) & 63, wv = (t2 >> 9) & 3, kc = t2 >> 11; // kc < 72
            int m = wv * 16 + (lane & 15);
            int n = (kc & 7) * 32 + (lane >> 4) * 8 + i;
            wd1f[t2] = f2bf(w_d1[m * 2304 + n * 9 + (kc >> 3)]);
        } else if (tt < 589824 + 147456 + 16384) {
            int t3 = tt - (589824 + 147456);
            int i = t3 & 7, lane = (t3 >> 3) & 63, wv = (t3 >> 9) & 3, s = t3 >> 11;  // s < 8
            int m = wv * 16 + (lane & 15);
            int n = s * 32 + (lane >> 4) * 8 + i;
            wc1f[t3] = f2bf(w_c1[m * 256 + n]);
        } else if (tt < 589824 + 147456 + 32768) {
            int t4 = tt - (589824 + 147456 + 16384);
            int i = t4 & 7, lane = (t4 >> 3) & 63, ot = (t4 >> 9) & 15, s = t4 >> 13; // s < 2
            int o = ot * 16 + (lane & 15);
            int kk = s * 32 + (lane >> 4) * 8 + i;
            wc2f[t4] = f2bf(w_c2[o * 64 + kk]);
        }
        return;
    }
    const int bid = blockIdx.x - 3008;                        // 0..511
    const int rw = ((bid & 7) << 6) + (bid >> 3);
    const int b = rw >> 6, hr = rw & 63;
    const int hp = hr + 1;
    #define XI(HP, NP, WP) ((((size_t)(b) * 66 + (HP)) * 32 + (NP)) * 66 + (WP)) * 8
    if (tid < 64) {   // zero wp borders for this row
        int np = tid & 31, wp = (tid & 32) ? 65 : 0;
        *(i32x4*)(xT8 + XI(hp, np, wp)) = i32x4{0, 0, 0, 0};
    }
    if (hr == 0) {    // zero full hp=0,65 planes for this b
        for (int i = tid; i < 2 * 32 * 66; i += 256) {
            int pl = (i >= 32 * 66) ? 65 : 0;
            int rem = (i >= 32 * 66) ? i - 32 * 66 : i;
            int np = rem / 66, wp = rem - np * 66;
            *(i32x4*)(xT8 + XI(pl, np, wp)) = i32x4{0, 0, 0, 0};
        }
    }
    const int dn = tid >> 6, w = tid & 63;
    for (int p = 0; p < 4; ++p) {
        __syncthreads();
        #pragma unroll
        for (int jj = 0; jj < 16; ++jj) {
            int n = p * 64 + dn * 16 + jj;
            t[w * 74 + dn * 16 + jj] = f2bf(x[(((size_t)(b * 256 + n) * 64) + hr) * 64 + w]);
        }
        __syncthreads();
        #pragma unroll
        for (int q = 0; q < 2; ++q) {
            int nl = q * 4 + dn;
            *(bf16x8*)(xT8 + XI(hp, p * 8 + nl, w + 1)) = *(const bf16x8*)(t + w * 74 + nl * 8);
        }
    }
    #undef XI
}

// ---------------- fused kernel: branch phase -> K-loop phase (same row, zero global round-trip) ----
// LDS: ent [64][264] bf16 [0, 33792) persists both phases
//      yc  [64][72]  bf16 [33792, 43008)  | phase 1 only
//      ydl [64][67]  f32  [43008, 60160)  | phase 1 only
//      zq0..3 (4KB each)  [33792, 50176)  | phase 2 (overlays dead yc/ydl)
//      ekl [9][64]   f32  [60160, 62464)  | written phase 1 (d-pass), read phase 2
#define FZ_YC    33792
#define FZ_YD    43008
#define FZ_ZQ    33792
#define FZ_EKL   60160
#define FZ_TOTAL 62464

__global__ __launch_bounds__(512, 4) void k_fused(const short* __restrict__ xT8,
        const float* __restrict__ b_c1, const float* __restrict__ b_c2,
        const float* __restrict__ b_d1, const float* __restrict__ w_d2, const float* __restrict__ b_d2,
        const short* __restrict__ wc1f, const short* __restrict__ wc2f, const short* __restrict__ wd1f,
        const short* __restrict__ Wf, float* __restrict__ out) {
    extern __shared__ char smem[];
    short* ent = (short*)smem;
    short* yc  = (short*)(smem + FZ_YC);
    float* ydl = (float*)(smem + FZ_YD);
    short* zqb = (short*)(smem + FZ_ZQ);       // zq[i] = zqb + i*2048 shorts
    float* ekl = (float*)(smem + FZ_EKL);

    const int rw = ((blockIdx.x & 7) << 6) + (blockIdx.x >> 3);  // XCD x <- batch x
    const int b = rw >> 6, h = rw & 63;
    const int tid = threadIdx.x;
    const int lane = tid & 63, wave = tid >> 6;
    const int l16 = lane & 15, lg = lane >> 4;
    const int wn = wave & 3, wm = wave >> 2;   // 2 (M) x 4 (N), phase 1
    const int cm = wn * 16 + l16;
    const size_t b66h = (size_t)(b * 66 + h);
    const int wcol = wm * 32 + l16;

    // ================= phase 1: branch =================
    #define CONV_A(DST, KC) {                                                           \
        int k9_ = (KC) >> 3;                                                            \
        int kh_ = (k9_ * 11) >> 5, kw_ = k9_ - 3 * kh_;                                 \
        const short* xa_ = xT8 + (((b66h + kh_) * 32 + ((KC) & 7) * 4 + lg) * 66        \
                                  + wcol + kw_) * 8;                                    \
        DST[0] = *(const bf16x8*)(xa_);                                                 \
        DST[1] = *(const bf16x8*)(xa_ + 128);                                           \
    }

    // ---- GEMM1: yc = relu(x . w_c1^T + b_c1)
    {
        f32x4 acc[2] = {};
        const short* wp_ = wc1f + wn * 512 + lane * 8;
        const short* xg1 = xT8 + (((b66h + 1) * 32 + lg) * 66 + wcol + 1) * 8;  // + s*2112
        bf16x8 bcur = *(const bf16x8*)(wp_);
        bf16x8 a0 = *(const bf16x8*)(xg1), a1 = *(const bf16x8*)(xg1 + 128);
        #pragma unroll
        for (int s = 0; s < 8; ++s) {
            bf16x8 bc = bcur, c0 = a0, c1 = a1;
            if (s < 7) {
                bcur = *(const bf16x8*)(wp_ + (s + 1) * 2048);
                a0 = *(const bf16x8*)(xg1 + (s + 1) * 2112);
                a1 = *(const bf16x8*)(xg1 + (s + 1) * 2112 + 128);
            }
            acc[0] = __builtin_amdgcn_mfma_f32_16x16x32_bf16(c0, bc, acc[0], 0, 0, 0);
            acc[1] = __builtin_amdgcn_mfma_f32_16x16x32_bf16(c1, bc, acc[1], 0, 0, 0);
        }
        float bias = b_c1[cm];
        #pragma unroll
        for (int mt = 0; mt < 2; ++mt)
            #pragma unroll
            for (int r = 0; r < 4; ++r) {
                int px = wm * 32 + mt * 16 + lg * 4 + r;
                float v = acc[mt][r] + bias;
                yc[px * 72 + cm] = f2bf(v > 0.f ? v : 0.f);
            }
    }

    // ---- conv GEMM: yd = relu(conv3x3 + b_d1); depth-3 prefetch, 3-way unroll
    {
        f32x4 acc[2] = {};
        const short* wp_ = wd1f + wn * 512 + lane * 8;   // kc stride 2048
        bf16x8 b0 = *(const bf16x8*)(wp_);
        bf16x8 b1 = *(const bf16x8*)(wp_ + 2048);
        bf16x8 b2 = *(const bf16x8*)(wp_ + 4096);
        bf16x8 aA[2], aB[2], aC[2];
        CONV_A(aA, 0) CONV_A(aB, 1) CONV_A(aC, 2)
        for (int kc = 0; kc < 72; kc += 3) {
            {
                bf16x8 c0 = aA[0], c1 = aA[1], bc = b0;
                int cn = (kc + 3 < 72) ? kc + 3 : 71;
                CONV_A(aA, cn)
                b0 = *(const bf16x8*)(wp_ + cn * 2048);
                acc[0] = __builtin_amdgcn_mfma_f32_16x16x32_bf16(c0, bc, acc[0], 0, 0, 0);
                acc[1] = __builtin_amdgcn_mfma_f32_16x16x32_bf16(c1, bc, acc[1], 0, 0, 0);
            }
            {
                bf16x8 c0 = aB[0], c1 = aB[1], bc = b1;
                int cn = (kc + 4 < 72) ? kc + 4 : 71;
                CONV_A(aB, cn)
                b1 = *(const bf16x8*)(wp_ + cn * 2048);
                acc[0] = __builtin_amdgcn_mfma_f32_16x16x32_bf16(c0, bc, acc[0], 0, 0, 0);
                acc[1] = __builtin_amdgcn_mfma_f32_16x16x32_bf16(c1, bc, acc[1], 0, 0, 0);
            }
            {
                bf16x8 c0 = aC[0], c1 = aC[1], bc = b2;
                int cn = (kc + 5 < 72) ? kc + 5 : 71;
                CONV_A(aC, cn)
                b2 = *(const bf16x8*)(wp_ + cn * 2048);
                acc[0] = __builtin_amdgcn_mfma_f32_16x16x32_bf16(c0, bc, acc[0], 0, 0, 0);
                acc[1] = __builtin_amdgcn_mfma_f32_16x16x32_bf16(c1, bc, acc[1], 0, 0, 0);
            }
        }
        float bias = b_d1[cm];
        #pragma unroll
        for (int mt = 0; mt < 2; ++mt)
            #pragma unroll
            for (int r = 0; r < 4; ++r) {
                int px = wm * 32 + mt * 16 + lg * 4 + r;
                float v = acc[mt][r] + bias;
                ydl[px * 67 + cm] = v > 0.f ? v : 0.f;
            }
    }
    #undef CONV_A
    __syncthreads();   // yc + ydl ready

    // ---- GEMM2 ; ent = exp(-2c) (LDS)
    {
        f32x4 acc[2][4] = {};
        #pragma unroll
        for (int s = 0; s < 2; ++s) {
            int k0 = s * 32;
            bf16x8 afr[2], bfr[4];
            #pragma unroll
            for (int mt = 0; mt < 2; ++mt)
                afr[mt] = *(const bf16x8*)(yc + (wm * 32 + mt * 16 + l16) * 72 + k0 + lg * 8);
            #pragma unroll
            for (int nt = 0; nt < 4; ++nt)
                bfr[nt] = *(const bf16x8*)(wc2f + s * 8192 + (wn * 4 + nt) * 512 + lane * 8);
            #pragma unroll
            for (int mt = 0; mt < 2; ++mt)
                #pragma unroll
                for (int nt = 0; nt < 4; ++nt)
                    acc[mt][nt] = __builtin_amdgcn_mfma_f32_16x16x32_bf16(afr[mt], bfr[nt], acc[mt][nt], 0, 0, 0);
        }
        #pragma unroll
        for (int nt = 0; nt < 4; ++nt) {
            int nc = wn * 64 + nt * 16 + l16;
            float bias = b_c2[nc];
            #pragma unroll
            for (int mt = 0; mt < 2; ++mt)
                #pragma unroll
                for (int r = 0; r < 4; ++r) {
                    int px = wm * 32 + mt * 16 + lg * 4 + r;
                    float cv = acc[mt][nt][r] + bias;
                    ent[px * 264 + nc] = f2bf(exp2f(NEXP2 * cv));
                }
        }
    }

    // ---- d-pass: ekl[k][px] = exp(-2d) (LDS)
    for (int t = tid; t < 576; t += 512) {
        int k = t >> 6, px = t & 63;
        float sum = b_d2[k];
        const float* yr = ydl + px * 67;
        const float* wr = w_d2 + k * 64;
        #pragma unroll 8
        for (int m = 0; m < 64; ++m) sum += yr[m] * wr[m];
        ekl[t] = exp2f(NEXP2 * sum);
    }
    __syncthreads();   // ent + ekl ready; yc/ydl dead -> zq usable

    // ================= phase 2: K-loop =================
    const int zpx = lane;
    const int wh = wave >> 1, wl = wave & 1;
    const short* xb0 = xT8 + (b66h * 32 + wh) * 528 + zpx * 8 + wl * 4;
    bf16x4 e_regs[8];   // from LDS ent: n = c8*32 + wh*8 + wl*4 + j, px = lane
    {
        const short* entp = ent + lane * 264 + wh * 8 + wl * 4;
        #pragma unroll
        for (int c8 = 0; c8 < 8; ++c8) e_regs[c8] = *(const bf16x4*)(entp + c8 * 32);
    }
    const int zwoff = (zpx >> 4) * 512 + ((zpx & 15) + wh * 16) * 8 + wl * 4;
    const short* wb0 = Wf + (wave * 2 + 0) * 512 + lane * 8;
    const short* wb1 = Wf + (wave * 2 + 1) * 512 + lane * 8;

    #define ZQ(I) (zqb + (I) * 2048)

    bf16x4 xrA, xrB;
    #define XLOADA(KC2) {                                                               \
        int k3_ = (KC2) >> 3, c8_ = (KC2) & 7;                                          \
        int kh_ = (k3_ * 11) >> 5, kw_ = k3_ - 3 * kh_;                                 \
        xrA = *(const bf16x4*)(xb0 + kh_ * 16896 + c8_ * 2112 + kw_ * 8);               \
    }
    #define XLOADB(KC2) {                                                               \
        int k3_ = (KC2) >> 3, c8_ = (KC2) & 7;                                          \
        int kh_ = (k3_ * 11) >> 5, kw_ = k3_ - 3 * kh_;                                 \
        xrB = *(const bf16x4*)(xb0 + kh_ * 16896 + c8_ * 2112 + kw_ * 8);               \
    }
    #define ZBUILDX(ZBUF, EKROW, EIDX, XR) {                                            \
        bf16x4 er = e_regs[EIDX];                                                       \
        float ekv = ekl[(EKROW) * 64 + zpx];                                            \
        float q0 = __builtin_fmaf(ekv, bf2f(er[0]), 1.0f);                              \
        float q1 = __builtin_fmaf(ekv, bf2f(er[1]), 1.0f);                              \
        float q2 = __builtin_fmaf(ekv, bf2f(er[2]), 1.0f);                              \
        float q3 = __builtin_fmaf(ekv, bf2f(er[3]), 1.0f);                              \
        i32x2 zz;                                                                       \
        zz[0] = cvt_pk_bf16(bf2f(XR[0]) * __builtin_amdgcn_rcpf(q0),                    \
                            bf2f(XR[1]) * __builtin_amdgcn_rcpf(q1));                   \
        zz[1] = cvt_pk_bf16(bf2f(XR[2]) * __builtin_amdgcn_rcpf(q2),                    \
                            bf2f(XR[3]) * __builtin_amdgcn_rcpf(q3));                   \
        *(i32x2*)((ZBUF) + zwoff) = zz;                                                 \
    }

    // prologue
    bf16x8 Be[2], Bo[2];
    Be[0] = *(const bf16x8*)(wb0);          Be[1] = *(const bf16x8*)(wb1);
    Bo[0] = *(const bf16x8*)(wb0 + 8192);   Bo[1] = *(const bf16x8*)(wb1 + 8192);
    XLOADA(0) XLOADB(1)
    ZBUILDX(ZQ(0), 0, 0, xrA)
    ZBUILDX(ZQ(1), 0, 1, xrB)
    XLOADA(2) XLOADB(3)
    __syncthreads();          // z0,z1 visible

    f32x4 acc[4][2] = {};

    #define PHASE(C8, P1, P2, EKR) {                                                    \
        short* zE = ZQ((C8) & 3);                                                       \
        short* zO = ZQ(((C8) + 1) & 3);                                                 \
        bf16x8 afr[4];                                                                  \
        _Pragma("unroll")                                                               \
        for (int mt = 0; mt < 4; ++mt)                                                  \
            afr[mt] = *(const bf16x8*)(zE + mt * 512 + lane * 8);                       \
        __builtin_amdgcn_s_setprio(1);                                                  \
        _Pragma("unroll")                                                               \
        for (int mt = 0; mt < 4; ++mt) {                                                \
            acc[mt][0] = __builtin_amdgcn_mfma_f32_16x16x32_bf16(afr[mt], Be[0], acc[mt][0], 0, 0, 0); \
            acc[mt][1] = __builtin_amdgcn_mfma_f32_16x16x32_bf16(afr[mt], Be[1], acc[mt][1], 0, 0, 0); \
        }                                                                               \
        __builtin_amdgcn_s_setprio(0);                                                  \
        if (P1) {                                                                       \
            int kb2_ = (k3 * 8 + (C8) + 2) * 8192;                                      \
            Be[0] = *(const bf16x8*)(wb0 + kb2_);                                       \
            Be[1] = *(const bf16x8*)(wb1 + kb2_);                                       \
            ZBUILDX(ZQ(((C8) + 2) & 3), EKR, ((C8) + 2) & 7, xrA)                       \
        }                                                                               \
        if (P2) XLOADA(k3 * 8 + (C8) + 4)                                               \
        _Pragma("unroll")                                                               \
        for (int mt = 0; mt < 4; ++mt)                                                  \
            afr[mt] = *(const bf16x8*)(zO + mt * 512 + lane * 8);                       \
        __builtin_amdgcn_s_setprio(1);                                                  \
        _Pragma("unroll")                                                               \
        for (int mt = 0; mt < 4; ++mt) {                                                \
            acc[mt][0] = __builtin_amdgcn_mfma_f32_16x16x32_bf16(afr[mt], Bo[0], acc[mt][0], 0, 0, 0); \
            acc[mt][1] = __builtin_amdgcn_mfma_f32_16x16x32_bf16(afr[mt], Bo[1], acc[mt][1], 0, 0, 0); \
        }                                                                               \
        __builtin_amdgcn_s_setprio(0);                                                  \
        if (P1) {                                                                       \
            int kb3_ = (k3 * 8 + (C8) + 3) * 8192;                                      \
            Bo[0] = *(const bf16x8*)(wb0 + kb3_);                                       \
            Bo[1] = *(const bf16x8*)(wb1 + kb3_);                                       \
            ZBUILDX(ZQ(((C8) + 3) & 3), EKR, ((C8) + 3) & 7, xrB)                       \
        }                                                                               \
        if (P2) XLOADB(k3 * 8 + (C8) + 5)                                               \
        __syncthreads();                                                                \
    }

    for (int k3 = 0; k3 < 8; ++k3) {
        PHASE(0, 1, 1, k3) PHASE(2, 1, 1, k3)
        PHASE(4, 1, 1, k3) PHASE(6, 1, 1, k3 + 1)
    }
    {   // k3 = 8 tail: phases kc = 64,66,68,70
        const int k3 = 8;
        PHASE(0, 1, 1, k3) PHASE(2, 1, 1, k3)
        PHASE(4, 1, 0, k3) PHASE(6, 0, 0, k3)
    }
    #undef PHASE
    #undef ZBUILDX
    #undef XLOADA
    #undef XLOADB
    #undef ZQ

    // epilogue: o = wave*32 + nt*16 + l16 ; px = mt*16 + lg*4 + r
    #pragma unroll
    for (int mt = 0; mt < 4; ++mt)
        #pragma unroll
        for (int nt = 0; nt < 2; ++nt) {
            int o = wave * 32 + nt * 16 + l16;
            float* d = out + (((size_t)b * 256 + o) * 64 + h) * 64 + mt * 16 + lg * 4;
            *(f32x4*)d = acc[mt][nt];
        }
}

// ---------------- launcher ----------------
extern "C" void kernel_launch(void* const* d_in, const int* in_sizes, int n_in,
                              void* d_out, int out_size, void* d_ws, size_t ws_size,
                              hipStream_t stream) {
    const float* x    = (const float*)d_in[0];
    const float* w_c1 = (const float*)d_in[1];
    const float* b_c1 = (const float*)d_in[2];
    const float* w_c2 = (const float*)d_in[3];
    const float* b_c2 = (const float*)d_in[4];
    const float* w_d1 = (const float*)d_in[5];
    const float* b_d1 = (const float*)d_in[6];
    const float* w_d2 = (const float*)d_in[7];
    const float* b_d2 = (const float*)d_in[8];
    const float* Wt   = (const float*)d_in[9];
    float* out = (float*)d_out;
    char* ws = (char*)d_ws;

    short* wc1f = (short*)(ws + WS_WC1F);
    short* wc2f = (short*)(ws + WS_WC2F);
    short* wd1f = (short*)(ws + WS_WD1F);
    short* Wf   = (short*)(ws + WS_WF);
    short* xT8  = (short*)(ws + WS_XT);

    (void)hipFuncSetAttribute((const void*)k_fused, hipFuncAttributeMaxDynamicSharedMemorySize, FZ_TOTAL);

    k_prep_all<<<3520, 256, 0, stream>>>(Wt, w_d1, w_c1, w_c2, x, Wf, wd1f, wc1f, wc2f, xT8);
    k_fused<<<512, 512, FZ_TOTAL, stream>>>(xT8, b_c1, b_c2, b_d1, w_d2, b_d2,
                                            wc1f, wc2f, wd1f, Wf, out);
}